// Round 1
// baseline (4267.647 us; speedup 1.0000x reference)
//
#include <hip/hip_runtime.h>
#include <hip/hip_bf16.h>
#include <cmath>

#define NSEQ 480
#define SEQN 128
#define CDIM 256
#define NH 8
#define HD 32
#define TOPM 20

// ---------------------------------------------------------------------------
// K1: transpose (B, C, N) -> (B, N, C) and add pos_embed
// grid (480, 4, 8), block 256
__global__ __launch_bounds__(256) void prep_kernel(const float* __restrict__ RW,
                                                   const float* __restrict__ POS,
                                                   float* __restrict__ X) {
    int b = blockIdx.x, n0 = blockIdx.y * 32, c0 = blockIdx.z * 32;
    __shared__ float tile[32][33];
    int tx = threadIdx.x & 31, ty = threadIdx.x >> 5;  // 32 x 8
#pragma unroll
    for (int jj = 0; jj < 4; ++jj) {
        int c = c0 + ty + 8 * jj;
        tile[ty + 8 * jj][tx] = RW[((size_t)b * CDIM + c) * SEQN + n0 + tx];
    }
    __syncthreads();
#pragma unroll
    for (int jj = 0; jj < 4; ++jj) {
        int n = n0 + ty + 8 * jj;
        int c = c0 + tx;
        X[((size_t)b * SEQN + n) * CDIM + c] = tile[tx][ty + 8 * jj] + POS[n * CDIM + c];
    }
}

// ---------------------------------------------------------------------------
// K2: fused qkv + top-20 masked attention for one (sequence, head).
// grid (480, 8), block 256.  LDS usage: exactly 64 KiB.
__global__ __launch_bounds__(256) void attn_kernel(const float* __restrict__ X,
                                                   float* __restrict__ O,
                                                   const float* __restrict__ W,
                                                   const float* __restrict__ BIAS) {
    int b = blockIdx.x;
    int h = blockIdx.y;
    const float scale = 0.17677669529663687f;  // 1/sqrt(32)

    __shared__ float q_lds[SEQN * HD];   // q[n][d] (pre-scaled)
    __shared__ float kT_lds[HD * SEQN];  // k[c][d] stored at [d*128 + ((c+d)&127)]
    __shared__ float v_lds[SEQN * HD];   // v[n][d]
    __shared__ float s_lds[32 * SEQN];   // score chunk; doubles as xs[128][32] staging

    const int tid = threadIdx.x;
    const int d = tid & 31;
    const int g = tid >> 5;  // 0..7
    const float* Xb = X + (size_t)b * SEQN * CDIM;

    // ---- QKV: q/k/v[n][d] = sum_k x[n][k] * W[k][{0,256,512}+h*32+d] + bias ----
    float aq[16], ak[16], av[16];
#pragma unroll
    for (int i = 0; i < 16; ++i) { aq[i] = 0.f; ak[i] = 0.f; av[i] = 0.f; }
    const int jq = h * HD + d, jk = 256 + h * HD + d, jv = 512 + h * HD + d;

    for (int k0 = 0; k0 < CDIM; k0 += 32) {
        __syncthreads();  // protect s_lds (staging buffer) between iterations
#pragma unroll
        for (int ii = 0; ii < 16; ++ii) {
            int e = tid + 256 * ii;          // 4096 elements: xs[n][kk]
            int n = e >> 5, kk = e & 31;
            s_lds[e] = Xb[n * CDIM + k0 + kk];
        }
        __syncthreads();
#pragma unroll 4
        for (int kk = 0; kk < 32; ++kk) {
            int kg = k0 + kk;
            float wq = W[kg * 768 + jq];
            float wk = W[kg * 768 + jk];
            float wv = W[kg * 768 + jv];
#pragma unroll
            for (int i = 0; i < 16; ++i) {
                float xv = s_lds[(g * 16 + i) * 32 + kk];
                aq[i] = fmaf(xv, wq, aq[i]);
                ak[i] = fmaf(xv, wk, ak[i]);
                av[i] = fmaf(xv, wv, av[i]);
            }
        }
    }
    __syncthreads();
    {
        float bq = BIAS[jq], bk = BIAS[jk], bv = BIAS[jv];
#pragma unroll
        for (int i = 0; i < 16; ++i) {
            int n = g * 16 + i;
            q_lds[n * HD + d] = (aq[i] + bq) * scale;
            kT_lds[d * SEQN + ((n + d) & 127)] = ak[i] + bk;
            v_lds[n * HD + d] = av[i] + bv;
        }
    }
    __syncthreads();

    // ---- attention, 4 chunks of 32 query rows ----
    const int cq = tid & 31;  // phase A: columns cq*4 .. cq*4+3
    const int rh = tid >> 5;  // rows rh*4 .. rh*4+3 (local to chunk)

    for (int chunk = 0; chunk < 4; ++chunk) {
        int r0 = chunk * 32;

        // phase A: s[r][c] = q[r0+r] . k[c]
        {
            float acc[4][4];
#pragma unroll
            for (int u = 0; u < 4; ++u)
#pragma unroll
                for (int w = 0; w < 4; ++w) acc[u][w] = 0.f;
            for (int dd = 0; dd < HD; ++dd) {
                float qv[4], kv[4];
#pragma unroll
                for (int u = 0; u < 4; ++u) qv[u] = q_lds[(r0 + rh * 4 + u) * HD + dd];
#pragma unroll
                for (int w = 0; w < 4; ++w) kv[w] = kT_lds[dd * SEQN + ((cq * 4 + w + dd) & 127)];
#pragma unroll
                for (int u = 0; u < 4; ++u)
#pragma unroll
                    for (int w = 0; w < 4; ++w) acc[u][w] = fmaf(qv[u], kv[w], acc[u][w]);
            }
#pragma unroll
            for (int u = 0; u < 4; ++u)
#pragma unroll
                for (int w = 0; w < 4; ++w) {
                    int r = rh * 4 + u, c = cq * 4 + w;
                    s_lds[r * SEQN + ((c + r) & 127)] = acc[u][w];
                }
        }
        __syncthreads();

        // phase B: per-row top-20 threshold + masked softmax (rows = threads 0..31)
        if (tid < 32) {
            int r = tid;
            float top[TOPM];
#pragma unroll
            for (int j = 0; j < TOPM; ++j) top[j] = -3.4e38f;
            for (int i = 0; i < SEQN; ++i) {
                float v = s_lds[r * SEQN + ((i + r) & 127)];
                if (v > top[TOPM - 1]) {
                    top[TOPM - 1] = v;
#pragma unroll
                    for (int j = TOPM - 1; j > 0; --j) {
                        if (top[j] > top[j - 1]) { float t = top[j]; top[j] = top[j - 1]; top[j - 1] = t; }
                    }
                }
            }
            float kth = top[TOPM - 1], mx = top[0];
            float sum = 0.f;
            for (int i = 0; i < SEQN; ++i) {
                int idx = r * SEQN + ((i + r) & 127);
                float v = s_lds[idx];
                float wgt = (v >= kth) ? __expf(v - mx) : 0.f;
                sum += wgt;
                s_lds[idx] = wgt;
            }
            float inv = 1.f / sum;
            for (int i = 0; i < SEQN; ++i) {
                int idx = r * SEQN + ((i + r) & 127);
                s_lds[idx] *= inv;
            }
        }
        __syncthreads();

        // phase C: o[r][d] = sum_c a[r][c] * v[c][d]
        {
            float acc[4] = {0.f, 0.f, 0.f, 0.f};
            for (int c = 0; c < SEQN; ++c) {
                float vv = v_lds[c * HD + d];
#pragma unroll
                for (int u = 0; u < 4; ++u) {
                    int r = rh * 4 + u;
                    float av_ = s_lds[r * SEQN + ((c + r) & 127)];
                    acc[u] = fmaf(av_, vv, acc[u]);
                }
            }
#pragma unroll
            for (int u = 0; u < 4; ++u) {
                int r = r0 + rh * 4 + u;
                O[((size_t)b * SEQN + r) * CDIM + h * HD + d] = acc[u];
            }
        }
        __syncthreads();
    }
}

// ---------------------------------------------------------------------------
// K3: proj GEMM + bias + residual + LayerNorm, 16 tokens per block.
// grid (480, 8), block 256.
__global__ __launch_bounds__(256) void projln_kernel(const float* __restrict__ O,
                                                     float* __restrict__ X,
                                                     const float* __restrict__ W,
                                                     const float* __restrict__ PB,
                                                     const float* __restrict__ G,
                                                     const float* __restrict__ BB) {
    int b = blockIdx.x;
    int t0 = blockIdx.y * 16;
    __shared__ float T[16 * 256];
    __shared__ float red[2][16][16];
    __shared__ float mstat[16], rstdv[16];
    int tid = threadIdx.x;

#pragma unroll
    for (int ii = 0; ii < 16; ++ii) {
        int e = tid + 256 * ii;
        T[e] = O[((size_t)b * SEQN + t0 + (e >> 8)) * CDIM + (e & 255)];
    }
    __syncthreads();

    int j = tid;
    float acc[16];
#pragma unroll
    for (int i = 0; i < 16; ++i) acc[i] = 0.f;
    for (int k = 0; k < CDIM; ++k) {
        float w = W[k * CDIM + j];
#pragma unroll
        for (int i = 0; i < 16; ++i) acc[i] = fmaf(T[i * 256 + k], w, acc[i]);
    }
    float bias = PB[j];
    float vals[16];
#pragma unroll
    for (int i = 0; i < 16; ++i)
        vals[i] = acc[i] + bias + X[((size_t)b * SEQN + t0 + i) * CDIM + j];
    __syncthreads();  // everyone done reading T
#pragma unroll
    for (int i = 0; i < 16; ++i) T[i * 256 + j] = vals[i];
    __syncthreads();
    {
        int i2 = tid >> 4, sidx = tid & 15;
        float ps = 0.f, pq = 0.f;
#pragma unroll
        for (int t = 0; t < 16; ++t) {
            float u = T[i2 * 256 + sidx * 16 + t];
            ps += u;
            pq += u * u;
        }
        red[0][i2][sidx] = ps;
        red[1][i2][sidx] = pq;
    }
    __syncthreads();
    if (tid < 16) {
        float s1 = 0.f, s2 = 0.f;
#pragma unroll
        for (int t = 0; t < 16; ++t) { s1 += red[0][tid][t]; s2 += red[1][tid][t]; }
        float m = s1 * (1.f / 256.f);
        float var = s2 * (1.f / 256.f) - m * m;
        mstat[tid] = m;
        rstdv[tid] = rsqrtf(var + 1e-5f);
    }
    __syncthreads();
    float gj = G[j], bj = BB[j];
#pragma unroll
    for (int i = 0; i < 16; ++i) {
        float y = (vals[i] - mstat[i]) * rstdv[i] * gj + bj;
        X[((size_t)b * SEQN + t0 + i) * CDIM + j] = y;
    }
}

// ---------------------------------------------------------------------------
// K4: mean over tokens + classifier head. grid 480, block 256.
__global__ __launch_bounds__(256) void cls_kernel(const float* __restrict__ X,
                                                  const float* __restrict__ W1,
                                                  const float* __restrict__ B1,
                                                  const float* __restrict__ W2,
                                                  const float* __restrict__ B2,
                                                  float* __restrict__ OUT) {
    int b = blockIdx.x;
    __shared__ float xm[256];
    __shared__ float hred[128];
    int tid = threadIdx.x;
    float s = 0.f;
    for (int n = 0; n < SEQN; ++n) s += X[((size_t)b * SEQN + n) * CDIM + tid];
    xm[tid] = s * (1.f / 128.f);
    __syncthreads();
    if (tid < 128) {
        float a = B1[tid];
        for (int k = 0; k < CDIM; ++k) a = fmaf(xm[k], W1[k * 128 + tid], a);
        a = fmaxf(a, 0.f);
        hred[tid] = a * W2[tid];
    }
    __syncthreads();
    for (int off = 64; off > 0; off >>= 1) {
        if (tid < off) hred[tid] += hred[tid + off];
        __syncthreads();
    }
    if (tid == 0) OUT[b] = hred[0] + B2[0];
}

// ---------------------------------------------------------------------------
extern "C" void kernel_launch(void* const* d_in, const int* in_sizes, int n_in,
                              void* d_out, int out_size, void* d_ws, size_t ws_size,
                              hipStream_t stream) {
    const float* RW  = (const float*)d_in[0];
    const float* POS = (const float*)d_in[1];
    const float* CW1 = (const float*)d_in[2];
    const float* CB1 = (const float*)d_in[3];
    const float* CW2 = (const float*)d_in[4];
    const float* CB2 = (const float*)d_in[5];

    float* X = (float*)d_ws;                        // 480*128*256 f32 = 63 MB
    float* O = X + (size_t)NSEQ * SEQN * CDIM;      // 63 MB

    prep_kernel<<<dim3(NSEQ, 4, 8), 256, 0, stream>>>(RW, POS, X);

    for (int l = 0; l < 2; ++l) {
        const float* qw = (const float*)d_in[6 + 6 * l];
        const float* qb = (const float*)d_in[7 + 6 * l];
        const float* pw = (const float*)d_in[8 + 6 * l];
        const float* pb = (const float*)d_in[9 + 6 * l];
        const float* lg = (const float*)d_in[10 + 6 * l];
        const float* lb = (const float*)d_in[11 + 6 * l];
        attn_kernel<<<dim3(NSEQ, NH), 256, 0, stream>>>(X, O, qw, qb);
        projln_kernel<<<dim3(NSEQ, 8), 256, 0, stream>>>(O, X, pw, pb, lg, lb);
    }

    cls_kernel<<<NSEQ, 256, 0, stream>>>(X, CW1, CB1, CW2, CB2, (float*)d_out);
}

// Round 2
// 1775.491 us; speedup vs baseline: 2.4036x; 2.4036x over previous
//
#include <hip/hip_runtime.h>
#include <hip/hip_bf16.h>
#include <cmath>

#define NSEQ 480
#define SEQN 128
#define CDIM 256
#define NH 8
#define HD 32
#define TOPM 20

// ---------------------------------------------------------------------------
// K1: transpose (B, C, N) -> (B, N, C) and add pos_embed
__global__ __launch_bounds__(256) void prep_kernel(const float* __restrict__ RW,
                                                   const float* __restrict__ POS,
                                                   float* __restrict__ X) {
    int b = blockIdx.x, n0 = blockIdx.y * 32, c0 = blockIdx.z * 32;
    __shared__ float tile[32][33];
    int tx = threadIdx.x & 31, ty = threadIdx.x >> 5;
#pragma unroll
    for (int jj = 0; jj < 4; ++jj) {
        int c = c0 + ty + 8 * jj;
        tile[ty + 8 * jj][tx] = RW[((size_t)b * CDIM + c) * SEQN + n0 + tx];
    }
    __syncthreads();
#pragma unroll
    for (int jj = 0; jj < 4; ++jj) {
        int n = n0 + ty + 8 * jj;
        int c = c0 + tx;
        X[((size_t)b * SEQN + n) * CDIM + c] = tile[tx][ty + 8 * jj] + POS[n * CDIM + c];
    }
}

// ---------------------------------------------------------------------------
// K2: fused qkv + exact top-20 masked attention for one (sequence, head).
// grid (480, 8), block 256.  LDS = 75264 B -> 2 blocks/CU.
__global__ __launch_bounds__(256, 2) void attn_kernel(const float* __restrict__ X,
                                                      float* __restrict__ O,
                                                      const float* __restrict__ W,
                                                      const float* __restrict__ BIAS) {
    const int b = blockIdx.x;
    const int h = blockIdx.y;
    const float scale = 0.17677669529663687f;  // 1/sqrt(32)

    // d-major tiles, col index XOR-swizzled by ((d&7)<<2): conflict-free b128 reads
    __shared__ float qT[HD][SEQN];
    __shared__ float kT[HD][SEQN];
    __shared__ float vT[HD][SEQN];
    __shared__ float s[32][136];   // score chunk (padded for aligned float4)
    __shared__ float xs[16][136];  // QKV staging: xs[kk][n] = X[n][k0+kk]

    const int tid = threadIdx.x;
    const int d = tid & 31;
    const int g = tid >> 5;  // 0..7
    const int sw = (d & 7) << 2;
    const float* Xb = X + (size_t)b * SEQN * CDIM;

    // ---- QKV ----
    float aq[16], ak[16], av[16];
#pragma unroll
    for (int i = 0; i < 16; ++i) { aq[i] = 0.f; ak[i] = 0.f; av[i] = 0.f; }
    const int jq = h * HD + d, jk = 256 + h * HD + d, jv = 512 + h * HD + d;

    for (int k0 = 0; k0 < CDIM; k0 += 16) {
        if (k0) __syncthreads();
        // stage 128 rows x 16 k: transposed
        {
            const int q = tid & 3;
            const int nr = tid >> 2;  // 0..63
#pragma unroll
            for (int p = 0; p < 2; ++p) {
                int n = p * 64 + nr;
                float4 xv = *reinterpret_cast<const float4*>(&Xb[n * CDIM + k0 + q * 4]);
                xs[q * 4 + 0][n] = xv.x;
                xs[q * 4 + 1][n] = xv.y;
                xs[q * 4 + 2][n] = xv.z;
                xs[q * 4 + 3][n] = xv.w;
            }
        }
        __syncthreads();
#pragma unroll
        for (int kk = 0; kk < 16; ++kk) {
            int kg = k0 + kk;
            float wq = W[kg * 768 + jq];
            float wk = W[kg * 768 + jk];
            float wv = W[kg * 768 + jv];
#pragma unroll
            for (int ii = 0; ii < 4; ++ii) {
                float4 xv = *reinterpret_cast<const float4*>(&xs[kk][g * 16 + ii * 4]);
                aq[ii * 4 + 0] = fmaf(xv.x, wq, aq[ii * 4 + 0]);
                aq[ii * 4 + 1] = fmaf(xv.y, wq, aq[ii * 4 + 1]);
                aq[ii * 4 + 2] = fmaf(xv.z, wq, aq[ii * 4 + 2]);
                aq[ii * 4 + 3] = fmaf(xv.w, wq, aq[ii * 4 + 3]);
                ak[ii * 4 + 0] = fmaf(xv.x, wk, ak[ii * 4 + 0]);
                ak[ii * 4 + 1] = fmaf(xv.y, wk, ak[ii * 4 + 1]);
                ak[ii * 4 + 2] = fmaf(xv.z, wk, ak[ii * 4 + 2]);
                ak[ii * 4 + 3] = fmaf(xv.w, wk, ak[ii * 4 + 3]);
                av[ii * 4 + 0] = fmaf(xv.x, wv, av[ii * 4 + 0]);
                av[ii * 4 + 1] = fmaf(xv.y, wv, av[ii * 4 + 1]);
                av[ii * 4 + 2] = fmaf(xv.z, wv, av[ii * 4 + 2]);
                av[ii * 4 + 3] = fmaf(xv.w, wv, av[ii * 4 + 3]);
            }
        }
    }
    __syncthreads();
    {
        float bq = BIAS[jq], bk = BIAS[jk], bv = BIAS[jv];
#pragma unroll
        for (int i = 0; i < 16; ++i) {
            int n = g * 16 + i;
            qT[d][n ^ sw] = (aq[i] + bq) * scale;
            kT[d][n ^ sw] = ak[i] + bk;
            vT[d][n ^ sw] = av[i] + bv;
        }
    }
    __syncthreads();

    // ---- attention: 4 chunks of 32 query rows ----
    const int cq = tid & 31;  // phase A col quad
    const int rh = tid >> 5;  // phase A row group

    for (int chunk = 0; chunk < 4; ++chunk) {
        const int r0 = chunk * 32;

        // phase A: s[r][c] = q[r0+r] . k[c], float4-blocked 4x4 per thread
        {
            float acc[4][4];
#pragma unroll
            for (int u = 0; u < 4; ++u)
#pragma unroll
                for (int w = 0; w < 4; ++w) acc[u][w] = 0.f;
#pragma unroll 8
            for (int dd = 0; dd < HD; ++dd) {
                int swd = (dd & 7) << 2;
                float4 qv = *reinterpret_cast<const float4*>(&qT[dd][(r0 + rh * 4) ^ swd]);
                float4 kv = *reinterpret_cast<const float4*>(&kT[dd][(cq * 4) ^ swd]);
                acc[0][0] = fmaf(qv.x, kv.x, acc[0][0]);
                acc[0][1] = fmaf(qv.x, kv.y, acc[0][1]);
                acc[0][2] = fmaf(qv.x, kv.z, acc[0][2]);
                acc[0][3] = fmaf(qv.x, kv.w, acc[0][3]);
                acc[1][0] = fmaf(qv.y, kv.x, acc[1][0]);
                acc[1][1] = fmaf(qv.y, kv.y, acc[1][1]);
                acc[1][2] = fmaf(qv.y, kv.z, acc[1][2]);
                acc[1][3] = fmaf(qv.y, kv.w, acc[1][3]);
                acc[2][0] = fmaf(qv.z, kv.x, acc[2][0]);
                acc[2][1] = fmaf(qv.z, kv.y, acc[2][1]);
                acc[2][2] = fmaf(qv.z, kv.z, acc[2][2]);
                acc[2][3] = fmaf(qv.z, kv.w, acc[2][3]);
                acc[3][0] = fmaf(qv.w, kv.x, acc[3][0]);
                acc[3][1] = fmaf(qv.w, kv.y, acc[3][1]);
                acc[3][2] = fmaf(qv.w, kv.z, acc[3][2]);
                acc[3][3] = fmaf(qv.w, kv.w, acc[3][3]);
            }
#pragma unroll
            for (int u = 0; u < 4; ++u) {
                float4 sv = make_float4(acc[u][0], acc[u][1], acc[u][2], acc[u][3]);
                *reinterpret_cast<float4*>(&s[rh * 4 + u][cq * 4]) = sv;
            }
        }
        __syncthreads();

        // phase B: exact top-20 threshold (radix select on ordered keys) + softmax
        {
            const int r = tid >> 3;    // 0..31
            const int sub = tid & 7;   // 0..7, 16 cols each
            float v[16];
            unsigned int key[16];
#pragma unroll
            for (int jj = 0; jj < 4; ++jj) {
                float4 sv = *reinterpret_cast<const float4*>(&s[r][sub * 16 + jj * 4]);
                v[jj * 4 + 0] = sv.x; v[jj * 4 + 1] = sv.y;
                v[jj * 4 + 2] = sv.z; v[jj * 4 + 3] = sv.w;
            }
#pragma unroll
            for (int j = 0; j < 16; ++j) {
                unsigned int bb = __float_as_uint(v[j]);
                key[j] = (bb & 0x80000000u) ? ~bb : (bb | 0x80000000u);
            }
            // radix select: p = key of 20th largest (exact, tie-correct)
            unsigned int p = 0u;
#pragma unroll
            for (int bit = 31; bit >= 0; --bit) {
                unsigned int t = p | (1u << bit);
                int c = 0;
#pragma unroll
                for (int j = 0; j < 16; ++j) c += (key[j] >= t) ? 1 : 0;
                c += __shfl_xor(c, 1);
                c += __shfl_xor(c, 2);
                c += __shfl_xor(c, 4);
                if (c >= TOPM) p = t;
            }
            // row max
            float mx = v[0];
#pragma unroll
            for (int j = 1; j < 16; ++j) mx = fmaxf(mx, v[j]);
            mx = fmaxf(mx, __shfl_xor(mx, 1));
            mx = fmaxf(mx, __shfl_xor(mx, 2));
            mx = fmaxf(mx, __shfl_xor(mx, 4));
            // masked exp + sum
            float wv[16];
            float sum = 0.f;
#pragma unroll
            for (int j = 0; j < 16; ++j) {
                float e = (key[j] >= p) ? __expf(v[j] - mx) : 0.f;
                wv[j] = e;
                sum += e;
            }
            sum += __shfl_xor(sum, 1);
            sum += __shfl_xor(sum, 2);
            sum += __shfl_xor(sum, 4);
            float inv = 1.f / sum;
#pragma unroll
            for (int jj = 0; jj < 4; ++jj) {
                float4 sv = make_float4(wv[jj * 4 + 0] * inv, wv[jj * 4 + 1] * inv,
                                        wv[jj * 4 + 2] * inv, wv[jj * 4 + 3] * inv);
                *reinterpret_cast<float4*>(&s[r][sub * 16 + jj * 4]) = sv;
            }
        }
        __syncthreads();

        // phase C: o[r][d] = sum_c a[r][c] * v[c][d]
        {
            float acc[4] = {0.f, 0.f, 0.f, 0.f};
#pragma unroll 8
            for (int c0 = 0; c0 < SEQN; c0 += 4) {
                float4 vv = *reinterpret_cast<const float4*>(&vT[d][c0 ^ sw]);
#pragma unroll
                for (int u = 0; u < 4; ++u) {
                    float4 a4 = *reinterpret_cast<const float4*>(&s[g * 4 + u][c0]);
                    acc[u] = fmaf(a4.x, vv.x, acc[u]);
                    acc[u] = fmaf(a4.y, vv.y, acc[u]);
                    acc[u] = fmaf(a4.z, vv.z, acc[u]);
                    acc[u] = fmaf(a4.w, vv.w, acc[u]);
                }
            }
#pragma unroll
            for (int u = 0; u < 4; ++u) {
                int r = r0 + g * 4 + u;
                O[((size_t)b * SEQN + r) * CDIM + h * HD + d] = acc[u];
            }
        }
        __syncthreads();
    }
}

// ---------------------------------------------------------------------------
// K3: proj GEMM + bias + residual + LayerNorm, 16 tokens per block.
__global__ __launch_bounds__(256) void projln_kernel(const float* __restrict__ O,
                                                     float* __restrict__ X,
                                                     const float* __restrict__ W,
                                                     const float* __restrict__ PB,
                                                     const float* __restrict__ G,
                                                     const float* __restrict__ BB) {
    int b = blockIdx.x;
    int t0 = blockIdx.y * 16;
    __shared__ float T[16 * 256];
    __shared__ float red[2][16][16];
    __shared__ float mstat[16], rstdv[16];
    int tid = threadIdx.x;

#pragma unroll
    for (int ii = 0; ii < 16; ++ii) {
        int e = tid + 256 * ii;
        T[e] = O[((size_t)b * SEQN + t0 + (e >> 8)) * CDIM + (e & 255)];
    }
    __syncthreads();

    int j = tid;
    float acc[16];
#pragma unroll
    for (int i = 0; i < 16; ++i) acc[i] = 0.f;
    for (int k = 0; k < CDIM; ++k) {
        float w = W[k * CDIM + j];
#pragma unroll
        for (int i = 0; i < 16; ++i) acc[i] = fmaf(T[i * 256 + k], w, acc[i]);
    }
    float bias = PB[j];
    float vals[16];
#pragma unroll
    for (int i = 0; i < 16; ++i)
        vals[i] = acc[i] + bias + X[((size_t)b * SEQN + t0 + i) * CDIM + j];
    __syncthreads();
#pragma unroll
    for (int i = 0; i < 16; ++i) T[i * 256 + j] = vals[i];
    __syncthreads();
    {
        int i2 = tid >> 4, sidx = tid & 15;
        float ps = 0.f, pq = 0.f;
#pragma unroll
        for (int t = 0; t < 16; ++t) {
            float u = T[i2 * 256 + sidx * 16 + t];
            ps += u;
            pq += u * u;
        }
        red[0][i2][sidx] = ps;
        red[1][i2][sidx] = pq;
    }
    __syncthreads();
    if (tid < 16) {
        float s1 = 0.f, s2 = 0.f;
#pragma unroll
        for (int t = 0; t < 16; ++t) { s1 += red[0][tid][t]; s2 += red[1][tid][t]; }
        float m = s1 * (1.f / 256.f);
        float var = s2 * (1.f / 256.f) - m * m;
        mstat[tid] = m;
        rstdv[tid] = rsqrtf(var + 1e-5f);
    }
    __syncthreads();
    float gj = G[j], bj = BB[j];
#pragma unroll
    for (int i = 0; i < 16; ++i) {
        float y = (vals[i] - mstat[i]) * rstdv[i] * gj + bj;
        X[((size_t)b * SEQN + t0 + i) * CDIM + j] = y;
    }
}

// ---------------------------------------------------------------------------
// K4: mean over tokens + classifier head. grid 480, block 256.
__global__ __launch_bounds__(256) void cls_kernel(const float* __restrict__ X,
                                                  const float* __restrict__ W1,
                                                  const float* __restrict__ B1,
                                                  const float* __restrict__ W2,
                                                  const float* __restrict__ B2,
                                                  float* __restrict__ OUT) {
    int b = blockIdx.x;
    __shared__ float xm[256];
    __shared__ float hred[128];
    int tid = threadIdx.x;
    float sm = 0.f;
    for (int n = 0; n < SEQN; ++n) sm += X[((size_t)b * SEQN + n) * CDIM + tid];
    xm[tid] = sm * (1.f / 128.f);
    __syncthreads();
    if (tid < 128) {
        float a = B1[tid];
        for (int k = 0; k < CDIM; ++k) a = fmaf(xm[k], W1[k * 128 + tid], a);
        a = fmaxf(a, 0.f);
        hred[tid] = a * W2[tid];
    }
    __syncthreads();
    for (int off = 64; off > 0; off >>= 1) {
        if (tid < off) hred[tid] += hred[tid + off];
        __syncthreads();
    }
    if (tid == 0) OUT[b] = hred[0] + B2[0];
}

// ---------------------------------------------------------------------------
extern "C" void kernel_launch(void* const* d_in, const int* in_sizes, int n_in,
                              void* d_out, int out_size, void* d_ws, size_t ws_size,
                              hipStream_t stream) {
    const float* RW  = (const float*)d_in[0];
    const float* POS = (const float*)d_in[1];
    const float* CW1 = (const float*)d_in[2];
    const float* CB1 = (const float*)d_in[3];
    const float* CW2 = (const float*)d_in[4];
    const float* CB2 = (const float*)d_in[5];

    float* X = (float*)d_ws;
    float* O = X + (size_t)NSEQ * SEQN * CDIM;

    prep_kernel<<<dim3(NSEQ, 4, 8), 256, 0, stream>>>(RW, POS, X);

    for (int l = 0; l < 2; ++l) {
        const float* qw = (const float*)d_in[6 + 6 * l];
        const float* qb = (const float*)d_in[7 + 6 * l];
        const float* pw = (const float*)d_in[8 + 6 * l];
        const float* pb = (const float*)d_in[9 + 6 * l];
        const float* lg = (const float*)d_in[10 + 6 * l];
        const float* lb = (const float*)d_in[11 + 6 * l];
        attn_kernel<<<dim3(NSEQ, NH), 256, 0, stream>>>(X, O, qw, qb);
        projln_kernel<<<dim3(NSEQ, 8), 256, 0, stream>>>(O, X, pw, pb, lg, lb);
    }

    cls_kernel<<<NSEQ, 256, 0, stream>>>(X, CW1, CB1, CW2, CB2, (float*)d_out);
}

// Round 3
// 1187.920 us; speedup vs baseline: 3.5925x; 1.4946x over previous
//
#include <hip/hip_runtime.h>
#include <hip/hip_bf16.h>
#include <cmath>

#define NSEQ 480
#define SEQN 128
#define CDIM 256
#define NH 8
#define HD 32
#define TOPM 20

typedef float f32x4 __attribute__((ext_vector_type(4)));
typedef short bf16x8 __attribute__((ext_vector_type(8)));

__device__ __forceinline__ unsigned short bf16_rn(float x) {
    unsigned int u = __float_as_uint(x);
    unsigned int r = (u + 0x7FFFu + ((u >> 16) & 1u)) >> 16;
    return (unsigned short)r;
}
__device__ __forceinline__ float bf16f(unsigned short h) {
    return __uint_as_float(((unsigned int)h) << 16);
}
__device__ __forceinline__ unsigned int okey(float v) {
    unsigned int u = __float_as_uint(v);
    return (u >> 31) ? ~u : (u | 0x80000000u);
}
__device__ __forceinline__ float okey_inv(unsigned int k) {
    return __uint_as_float((k >> 31) ? (k & 0x7FFFFFFFu) : ~k);
}

// ---------------------------------------------------------------------------
// K1: transpose (B, C, N) -> (B, N, C) and add pos_embed
__global__ __launch_bounds__(256) void prep_kernel(const float* __restrict__ RW,
                                                   const float* __restrict__ POS,
                                                   float* __restrict__ X) {
    int b = blockIdx.x, n0 = blockIdx.y * 32, c0 = blockIdx.z * 32;
    __shared__ float tile[32][33];
    int tx = threadIdx.x & 31, ty = threadIdx.x >> 5;
#pragma unroll
    for (int jj = 0; jj < 4; ++jj) {
        int c = c0 + ty + 8 * jj;
        tile[ty + 8 * jj][tx] = RW[((size_t)b * CDIM + c) * SEQN + n0 + tx];
    }
    __syncthreads();
#pragma unroll
    for (int jj = 0; jj < 4; ++jj) {
        int n = n0 + ty + 8 * jj;
        int c = c0 + tx;
        X[((size_t)b * SEQN + n) * CDIM + c] = tile[tx][ty + 8 * jj] + POS[n * CDIM + c];
    }
}

// ---------------------------------------------------------------------------
// K1b: W (256,768) -> Wt_hi/Wt_lo [768][256] bf16 split.  grid (8,24), block 256.
__global__ __launch_bounds__(256) void wsplit_kernel(const float* __restrict__ W,
                                                     unsigned short* __restrict__ WtHi,
                                                     unsigned short* __restrict__ WtLo) {
    int k0 = blockIdx.x * 32, j0 = blockIdx.y * 32;
    __shared__ float tile[32][33];
    int tx = threadIdx.x & 31, ty = threadIdx.x >> 5;
#pragma unroll
    for (int jj = 0; jj < 4; ++jj)
        tile[ty + 8 * jj][tx] = W[(size_t)(k0 + ty + 8 * jj) * 768 + j0 + tx];
    __syncthreads();
#pragma unroll
    for (int jj = 0; jj < 4; ++jj) {
        float v = tile[tx][ty + 8 * jj];
        unsigned short hi = bf16_rn(v);
        unsigned short lo = bf16_rn(v - bf16f(hi));
        size_t idx = (size_t)(j0 + ty + 8 * jj) * 256 + k0 + tx;
        WtHi[idx] = hi;
        WtLo[idx] = lo;
    }
}

// ---------------------------------------------------------------------------
// K2: fused qkv + exact top-20 attention, all GEMMs on split-bf16 MFMA.
// grid 3840 (bid = h*480 + b), block 256 (4 waves).  LDS = 48 KiB.
__global__ __launch_bounds__(256) void attn_kernel(const float* __restrict__ X,
                                                   float* __restrict__ O,
                                                   const unsigned short* __restrict__ WtHi,
                                                   const unsigned short* __restrict__ WtLo,
                                                   const float* __restrict__ BIAS) {
    const int bid = blockIdx.x;
    const int h = bid / NSEQ;
    const int b = bid - h * NSEQ;
    const float scale = 0.17677669529663687f;  // 1/sqrt(32)

    // q/k: row-major [128][32] bf16, col swizzled: d' = d ^ (((row>>1)&3)<<3)
    // vT : [32][128] bf16, col swizzled: t' = t ^ ((d&7)<<3)
    __shared__ unsigned short qh[SEQN * HD], ql[SEQN * HD];
    __shared__ unsigned short kh[SEQN * HD], kl[SEQN * HD];
    __shared__ unsigned short vh[HD * SEQN], vl[HD * SEQN];

    const int tid = threadIdx.x;
    const int w = tid >> 6;    // wave 0..3 -> token rows [w*32, w*32+32)
    const int l = tid & 63;
    const int l15 = l & 15;
    const int sct = l >> 4;    // 0..3
    const float* Xb = X + (size_t)b * SEQN * CDIM;

    // ================= Phase 1: QKV via MFMA =================
    f32x4 acc[2][6];
#pragma unroll
    for (int mi = 0; mi < 2; ++mi)
#pragma unroll
        for (int ni = 0; ni < 6; ++ni) acc[mi][ni] = (f32x4){0.f, 0.f, 0.f, 0.f};

#pragma unroll 2
    for (int ks = 0; ks < 8; ++ks) {
        const int kb = ks * 32;
        bf16x8 ahi[2], alo[2];
#pragma unroll
        for (int mi = 0; mi < 2; ++mi) {
            int row = w * 32 + mi * 16 + l15;
            const float* px = Xb + row * CDIM + kb + sct * 8;
            float4 x0 = *reinterpret_cast<const float4*>(px);
            float4 x1 = *reinterpret_cast<const float4*>(px + 4);
            float xv[8] = {x0.x, x0.y, x0.z, x0.w, x1.x, x1.y, x1.z, x1.w};
#pragma unroll
            for (int e = 0; e < 8; ++e) {
                unsigned short hi = bf16_rn(xv[e]);
                ahi[mi][e] = (short)hi;
                alo[mi][e] = (short)bf16_rn(xv[e] - bf16f(hi));
            }
        }
#pragma unroll
        for (int ni = 0; ni < 6; ++ni) {
            int j = ((ni >> 1) << 8) + h * HD + ((ni & 1) << 4) + l15;
            const int off = j * 256 + kb + sct * 8;
            bf16x8 bh = *reinterpret_cast<const bf16x8*>(WtHi + off);
            bf16x8 bl = *reinterpret_cast<const bf16x8*>(WtLo + off);
#pragma unroll
            for (int mi = 0; mi < 2; ++mi) {
                acc[mi][ni] = __builtin_amdgcn_mfma_f32_16x16x32_bf16(ahi[mi], bh, acc[mi][ni], 0, 0, 0);
                acc[mi][ni] = __builtin_amdgcn_mfma_f32_16x16x32_bf16(ahi[mi], bl, acc[mi][ni], 0, 0, 0);
                acc[mi][ni] = __builtin_amdgcn_mfma_f32_16x16x32_bf16(alo[mi], bh, acc[mi][ni], 0, 0, 0);
            }
        }
    }
    // store q/k/vT to LDS with bias (+scale on q), split bf16
#pragma unroll
    for (int ni = 0; ni < 6; ++ni) {
        int sel = ni >> 1;
        int dcol = ((ni & 1) << 4) + l15;
        float bias = BIAS[(sel << 8) + h * HD + dcol];
#pragma unroll
        for (int mi = 0; mi < 2; ++mi) {
#pragma unroll
            for (int r = 0; r < 4; ++r) {
                int token = w * 32 + mi * 16 + sct * 4 + r;
                float v = acc[mi][ni][r] + bias;
                if (sel == 0) {
                    v *= scale;
                    unsigned short hi = bf16_rn(v);
                    int idx = token * HD + (dcol ^ (((token >> 1) & 3) << 3));
                    qh[idx] = hi;
                    ql[idx] = bf16_rn(v - bf16f(hi));
                } else if (sel == 1) {
                    unsigned short hi = bf16_rn(v);
                    int idx = token * HD + (dcol ^ (((token >> 1) & 3) << 3));
                    kh[idx] = hi;
                    kl[idx] = bf16_rn(v - bf16f(hi));
                } else {
                    unsigned short hi = bf16_rn(v);
                    int idx = dcol * SEQN + (token ^ ((dcol & 7) << 3));
                    vh[idx] = hi;
                    vl[idx] = bf16_rn(v - bf16f(hi));
                }
            }
        }
    }
    __syncthreads();

    // ================= Phase 2: S^T = K·Q^T (per-wave), in-register softmax ===
    f32x4 sacc[8][2];
#pragma unroll
    for (int mi = 0; mi < 8; ++mi)
#pragma unroll
        for (int ni = 0; ni < 2; ++ni) sacc[mi][ni] = (f32x4){0.f, 0.f, 0.f, 0.f};

    bf16x8 qfh[2], qfl[2];
#pragma unroll
    for (int ni = 0; ni < 2; ++ni) {
        int qrow = w * 32 + (ni << 4) + l15;
        int off = qrow * HD + ((sct * 8) ^ (((qrow >> 1) & 3) << 3));
        qfh[ni] = *reinterpret_cast<const bf16x8*>(qh + off);
        qfl[ni] = *reinterpret_cast<const bf16x8*>(ql + off);
    }
#pragma unroll
    for (int mi = 0; mi < 8; ++mi) {
        int krow = (mi << 4) + l15;
        int off = krow * HD + ((sct * 8) ^ (((krow >> 1) & 3) << 3));
        bf16x8 kfh = *reinterpret_cast<const bf16x8*>(kh + off);
        bf16x8 kfl = *reinterpret_cast<const bf16x8*>(kl + off);
#pragma unroll
        for (int ni = 0; ni < 2; ++ni) {
            sacc[mi][ni] = __builtin_amdgcn_mfma_f32_16x16x32_bf16(kfh, qfh[ni], sacc[mi][ni], 0, 0, 0);
            sacc[mi][ni] = __builtin_amdgcn_mfma_f32_16x16x32_bf16(kfh, qfl[ni], sacc[mi][ni], 0, 0, 0);
            sacc[mi][ni] = __builtin_amdgcn_mfma_f32_16x16x32_bf16(kfl, qfh[ni], sacc[mi][ni], 0, 0, 0);
        }
    }
    // lane holds q-cols {w*32 + ni*16 + l15}, kv rows 16*mi + sct*4 + r
    unsigned int key[8][2][4];
#pragma unroll
    for (int mi = 0; mi < 8; ++mi)
#pragma unroll
        for (int ni = 0; ni < 2; ++ni)
#pragma unroll
            for (int r = 0; r < 4; ++r) key[mi][ni][r] = okey(sacc[mi][ni][r]);

    // exact top-20 threshold per q-row: radix select over 4 lanes (xor 16,32)
    unsigned int p0 = 0u, p1 = 0u;
    for (int bit = 31; bit >= 0; --bit) {
        unsigned int t0 = p0 | (1u << bit), t1 = p1 | (1u << bit);
        int c0 = 0, c1 = 0;
#pragma unroll
        for (int mi = 0; mi < 8; ++mi)
#pragma unroll
            for (int r = 0; r < 4; ++r) {
                c0 += (key[mi][0][r] >= t0) ? 1 : 0;
                c1 += (key[mi][1][r] >= t1) ? 1 : 0;
            }
        int m = c0 | (c1 << 8);
        m += __shfl_xor(m, 16);
        m += __shfl_xor(m, 32);
        if ((m & 255) >= TOPM) p0 = t0;
        if ((m >> 8) >= TOPM) p1 = t1;
    }
    // row max (key domain, monotone)
    unsigned int km0 = 0u, km1 = 0u;
#pragma unroll
    for (int mi = 0; mi < 8; ++mi)
#pragma unroll
        for (int r = 0; r < 4; ++r) {
            km0 = max(km0, key[mi][0][r]);
            km1 = max(km1, key[mi][1][r]);
        }
    km0 = max(km0, (unsigned int)__shfl_xor((int)km0, 16));
    km0 = max(km0, (unsigned int)__shfl_xor((int)km0, 32));
    km1 = max(km1, (unsigned int)__shfl_xor((int)km1, 16));
    km1 = max(km1, (unsigned int)__shfl_xor((int)km1, 32));
    float mx0 = okey_inv(km0), mx1 = okey_inv(km1);

    float wgt[8][2][4];
    float s0 = 0.f, s1 = 0.f;
#pragma unroll
    for (int mi = 0; mi < 8; ++mi)
#pragma unroll
        for (int r = 0; r < 4; ++r) {
            unsigned int k0v = key[mi][0][r], k1v = key[mi][1][r];
            float e0 = (k0v >= p0) ? __expf(okey_inv(k0v) - mx0) : 0.f;
            float e1 = (k1v >= p1) ? __expf(okey_inv(k1v) - mx1) : 0.f;
            wgt[mi][0][r] = e0;
            wgt[mi][1][r] = e1;
            s0 += e0;
            s1 += e1;
        }
    s0 += __shfl_xor(s0, 16);
    s0 += __shfl_xor(s0, 32);
    s1 += __shfl_xor(s1, 16);
    s1 += __shfl_xor(s1, 32);
    float i0 = 1.f / s0, i1 = 1.f / s1;
#pragma unroll
    for (int mi = 0; mi < 8; ++mi)
#pragma unroll
        for (int r = 0; r < 4; ++r) {
            wgt[mi][0][r] *= i0;
            wgt[mi][1][r] *= i1;
        }

    // ================= Phase 3: O = softmax(S)·V via MFMA =================
    f32x4 oacc[2][2];
#pragma unroll
    for (int mi = 0; mi < 2; ++mi)
#pragma unroll
        for (int ni = 0; ni < 2; ++ni) oacc[mi][ni] = (f32x4){0.f, 0.f, 0.f, 0.f};

#pragma unroll
    for (int k = 0; k < 4; ++k) {
        bf16x8 bh[2], bl[2];
#pragma unroll
        for (int nio = 0; nio < 2; ++nio) {
            int drow = (nio << 4) + l15;
            int off = drow * SEQN + ((k * 32 + sct * 8) ^ ((drow & 7) << 3));
            bh[nio] = *reinterpret_cast<const bf16x8*>(vh + off);
            bl[nio] = *reinterpret_cast<const bf16x8*>(vl + off);
        }
#pragma unroll
        for (int mio = 0; mio < 2; ++mio) {
            // A-frag: weights of q-row (w*32 + mio*16 + l15), kv = k*32 + sct*8 + e
            bf16x8 ah, al;
#pragma unroll
            for (int e = 0; e < 8; ++e) {
                int src = l15 + ((sct & 1) << 5) + ((e & 4) << 2);
                float v0 = __shfl(wgt[2 * k][mio][e & 3], src);
                float v1 = __shfl(wgt[2 * k + 1][mio][e & 3], src);
                float v = (l >= 32) ? v1 : v0;
                unsigned short hi = bf16_rn(v);
                ah[e] = (short)hi;
                al[e] = (short)bf16_rn(v - bf16f(hi));
            }
#pragma unroll
            for (int nio = 0; nio < 2; ++nio) {
                oacc[mio][nio] = __builtin_amdgcn_mfma_f32_16x16x32_bf16(ah, bh[nio], oacc[mio][nio], 0, 0, 0);
                oacc[mio][nio] = __builtin_amdgcn_mfma_f32_16x16x32_bf16(ah, bl[nio], oacc[mio][nio], 0, 0, 0);
                oacc[mio][nio] = __builtin_amdgcn_mfma_f32_16x16x32_bf16(al, bh[nio], oacc[mio][nio], 0, 0, 0);
            }
        }
    }
#pragma unroll
    for (int mio = 0; mio < 2; ++mio)
#pragma unroll
        for (int nio = 0; nio < 2; ++nio)
#pragma unroll
            for (int r = 0; r < 4; ++r) {
                int token = w * 32 + mio * 16 + sct * 4 + r;
                int d = (nio << 4) + l15;
                O[((size_t)b * SEQN + token) * CDIM + h * HD + d] = oacc[mio][nio][r];
            }
}

// ---------------------------------------------------------------------------
// K3: proj GEMM + bias + residual + LayerNorm, 16 tokens per block.
__global__ __launch_bounds__(256) void projln_kernel(const float* __restrict__ O,
                                                     float* __restrict__ X,
                                                     const float* __restrict__ W,
                                                     const float* __restrict__ PB,
                                                     const float* __restrict__ G,
                                                     const float* __restrict__ BB) {
    int b = blockIdx.x;
    int t0 = blockIdx.y * 16;
    __shared__ float T[16 * 256];
    __shared__ float red[2][16][16];
    __shared__ float mstat[16], rstdv[16];
    int tid = threadIdx.x;

#pragma unroll
    for (int ii = 0; ii < 16; ++ii) {
        int e = tid + 256 * ii;
        T[e] = O[((size_t)b * SEQN + t0 + (e >> 8)) * CDIM + (e & 255)];
    }
    __syncthreads();

    int j = tid;
    float acc[16];
#pragma unroll
    for (int i = 0; i < 16; ++i) acc[i] = 0.f;
    for (int k = 0; k < CDIM; ++k) {
        float w = W[k * CDIM + j];
#pragma unroll
        for (int i = 0; i < 16; ++i) acc[i] = fmaf(T[i * 256 + k], w, acc[i]);
    }
    float bias = PB[j];
    float vals[16];
#pragma unroll
    for (int i = 0; i < 16; ++i)
        vals[i] = acc[i] + bias + X[((size_t)b * SEQN + t0 + i) * CDIM + j];
    __syncthreads();
#pragma unroll
    for (int i = 0; i < 16; ++i) T[i * 256 + j] = vals[i];
    __syncthreads();
    {
        int i2 = tid >> 4, sidx = tid & 15;
        float ps = 0.f, pq = 0.f;
#pragma unroll
        for (int t = 0; t < 16; ++t) {
            float u = T[i2 * 256 + sidx * 16 + t];
            ps += u;
            pq += u * u;
        }
        red[0][i2][sidx] = ps;
        red[1][i2][sidx] = pq;
    }
    __syncthreads();
    if (tid < 16) {
        float s1 = 0.f, s2 = 0.f;
#pragma unroll
        for (int t = 0; t < 16; ++t) { s1 += red[0][tid][t]; s2 += red[1][tid][t]; }
        float m = s1 * (1.f / 256.f);
        float var = s2 * (1.f / 256.f) - m * m;
        mstat[tid] = m;
        rstdv[tid] = rsqrtf(var + 1e-5f);
    }
    __syncthreads();
    float gj = G[j], bj = BB[j];
#pragma unroll
    for (int i = 0; i < 16; ++i) {
        float y = (vals[i] - mstat[i]) * rstdv[i] * gj + bj;
        X[((size_t)b * SEQN + t0 + i) * CDIM + j] = y;
    }
}

// ---------------------------------------------------------------------------
// K4: mean over tokens + classifier head. grid 480, block 256.
__global__ __launch_bounds__(256) void cls_kernel(const float* __restrict__ X,
                                                  const float* __restrict__ W1,
                                                  const float* __restrict__ B1,
                                                  const float* __restrict__ W2,
                                                  const float* __restrict__ B2,
                                                  float* __restrict__ OUT) {
    int b = blockIdx.x;
    __shared__ float xm[256];
    __shared__ float hred[128];
    int tid = threadIdx.x;
    float sm = 0.f;
    for (int n = 0; n < SEQN; ++n) sm += X[((size_t)b * SEQN + n) * CDIM + tid];
    xm[tid] = sm * (1.f / 128.f);
    __syncthreads();
    if (tid < 128) {
        float a = B1[tid];
        for (int k = 0; k < CDIM; ++k) a = fmaf(xm[k], W1[k * 128 + tid], a);
        a = fmaxf(a, 0.f);
        hred[tid] = a * W2[tid];
    }
    __syncthreads();
    for (int off = 64; off > 0; off >>= 1) {
        if (tid < off) hred[tid] += hred[tid + off];
        __syncthreads();
    }
    if (tid == 0) OUT[b] = hred[0] + B2[0];
}

// ---------------------------------------------------------------------------
extern "C" void kernel_launch(void* const* d_in, const int* in_sizes, int n_in,
                              void* d_out, int out_size, void* d_ws, size_t ws_size,
                              hipStream_t stream) {
    const float* RW  = (const float*)d_in[0];
    const float* POS = (const float*)d_in[1];
    const float* CW1 = (const float*)d_in[2];
    const float* CB1 = (const float*)d_in[3];
    const float* CW2 = (const float*)d_in[4];
    const float* CB2 = (const float*)d_in[5];

    float* X = (float*)d_ws;
    float* O = X + (size_t)NSEQ * SEQN * CDIM;
    unsigned short* WtHi = (unsigned short*)(O + (size_t)NSEQ * SEQN * CDIM);
    unsigned short* WtLo = WtHi + (size_t)768 * 256;

    prep_kernel<<<dim3(NSEQ, 4, 8), 256, 0, stream>>>(RW, POS, X);

    for (int li = 0; li < 2; ++li) {
        const float* qw = (const float*)d_in[6 + 6 * li];
        const float* qb = (const float*)d_in[7 + 6 * li];
        const float* pw = (const float*)d_in[8 + 6 * li];
        const float* pb = (const float*)d_in[9 + 6 * li];
        const float* lg = (const float*)d_in[10 + 6 * li];
        const float* lb = (const float*)d_in[11 + 6 * li];
        wsplit_kernel<<<dim3(8, 24), 256, 0, stream>>>(qw, WtHi, WtLo);
        attn_kernel<<<NSEQ * NH, 256, 0, stream>>>(X, O, WtHi, WtLo, qb);
        projln_kernel<<<dim3(NSEQ, 8), 256, 0, stream>>>(O, X, pw, pb, lg, lb);
    }

    cls_kernel<<<NSEQ, 256, 0, stream>>>(X, CW1, CB1, CW2, CB2, (float*)d_out);
}

// Round 4
// 860.343 us; speedup vs baseline: 4.9604x; 1.3808x over previous
//
#include <hip/hip_runtime.h>
#include <hip/hip_bf16.h>
#include <cmath>

#define NSEQ 480
#define SEQN 128
#define CDIM 256
#define NH 8
#define HD 32
#define TOPM 20

typedef float f32x4 __attribute__((ext_vector_type(4)));
typedef short bf16x8 __attribute__((ext_vector_type(8)));

__device__ __forceinline__ unsigned short bf16_rn(float x) {
    unsigned int u = __float_as_uint(x);
    unsigned int r = (u + 0x7FFFu + ((u >> 16) & 1u)) >> 16;
    return (unsigned short)r;
}
__device__ __forceinline__ float bf16f(unsigned short h) {
    return __uint_as_float(((unsigned int)h) << 16);
}
__device__ __forceinline__ unsigned int okey(float v) {
    unsigned int u = __float_as_uint(v);
    return (u >> 31) ? ~u : (u | 0x80000000u);
}
__device__ __forceinline__ float okey_inv(unsigned int k) {
    return __uint_as_float((k >> 31) ? (k & 0x7FFFFFFFu) : ~k);
}
// pack two f32 -> u32 of 2 bf16 (lo16 = a, hi16 = b), RNE
__device__ __forceinline__ unsigned pk_bf16(float a, float b) {
    union { __hip_bfloat162 h; unsigned u; } cv;
    cv.h = __float22bfloat162_rn(make_float2(a, b));
    return cv.u;
}

// ---------------------------------------------------------------------------
// K1: transpose (B, C, N) -> (B, N, C), add pos_embed, emit split-bf16 planes
__global__ __launch_bounds__(256) void prep_kernel(const float* __restrict__ RW,
                                                   const float* __restrict__ POS,
                                                   unsigned short* __restrict__ XH,
                                                   unsigned short* __restrict__ XL) {
    int b = blockIdx.x, n0 = blockIdx.y * 32, c0 = blockIdx.z * 32;
    __shared__ float tile[32][33];
    int tx = threadIdx.x & 31, ty = threadIdx.x >> 5;
#pragma unroll
    for (int jj = 0; jj < 4; ++jj) {
        int c = c0 + ty + 8 * jj;
        tile[ty + 8 * jj][tx] = RW[((size_t)b * CDIM + c) * SEQN + n0 + tx];
    }
    __syncthreads();
#pragma unroll
    for (int jj = 0; jj < 4; ++jj) {
        int n = n0 + ty + 8 * jj;
        int c = c0 + tx;
        float val = tile[tx][ty + 8 * jj] + POS[n * CDIM + c];
        unsigned short hi = bf16_rn(val);
        size_t idx = (size_t)b * SEQN * CDIM + n * CDIM + c;
        XH[idx] = hi;
        XL[idx] = bf16_rn(val - bf16f(hi));
    }
}

// ---------------------------------------------------------------------------
// K1b: W (256,768) -> Wt_hi/Wt_lo [768][256] bf16 split.  grid (8,24), block 256.
__global__ __launch_bounds__(256) void wsplit_kernel(const float* __restrict__ W,
                                                     unsigned short* __restrict__ WtHi,
                                                     unsigned short* __restrict__ WtLo) {
    int k0 = blockIdx.x * 32, j0 = blockIdx.y * 32;
    __shared__ float tile[32][33];
    int tx = threadIdx.x & 31, ty = threadIdx.x >> 5;
#pragma unroll
    for (int jj = 0; jj < 4; ++jj)
        tile[ty + 8 * jj][tx] = W[(size_t)(k0 + ty + 8 * jj) * 768 + j0 + tx];
    __syncthreads();
#pragma unroll
    for (int jj = 0; jj < 4; ++jj) {
        float v = tile[tx][ty + 8 * jj];
        unsigned short hi = bf16_rn(v);
        unsigned short lo = bf16_rn(v - bf16f(hi));
        size_t idx = (size_t)(j0 + ty + 8 * jj) * 256 + k0 + tx;
        WtHi[idx] = hi;
        WtLo[idx] = lo;
    }
}

// ---------------------------------------------------------------------------
// K2: fused qkv + exact top-20 attention.  Q/K split-bf16 (3-term MFMA),
// V and P single-bf16.  grid 3840, bid = (b&7) + 8h + 64(b>>3) (XCD locality).
// block 256 (4 waves).  LDS = 40 KiB -> 4 blocks/CU.
__global__ __launch_bounds__(256, 4) void attn_kernel(
    const unsigned short* __restrict__ XHi, const unsigned short* __restrict__ XLo,
    float* __restrict__ O,
    const unsigned short* __restrict__ WtHi, const unsigned short* __restrict__ WtLo,
    const float* __restrict__ BIAS) {
    const int bid = blockIdx.x;
    const int h = (bid >> 3) & 7;
    const int b = ((bid >> 6) << 3) | (bid & 7);
    const float scale = 0.17677669529663687f;  // 1/sqrt(32)

    // q/k: row-major [128][32], col swizzle d' = d ^ (((tok>>1)&3)<<3)
    // vT : [32][128],  col swizzle t' = t ^ ((d&7)<<3)
    __shared__ unsigned short qh[SEQN * HD], ql[SEQN * HD];
    __shared__ unsigned short kh[SEQN * HD], kl[SEQN * HD];
    __shared__ unsigned short vh[HD * SEQN];

    const int tid = threadIdx.x;
    const int w = tid >> 6;    // wave 0..3 -> token rows [w*32, w*32+32)
    const int l = tid & 63;
    const int l15 = l & 15;
    const int sct = l >> 4;    // 0..3
    const size_t xbase = (size_t)b * SEQN * CDIM;

    // ================= Phase 1: QKV via MFMA =================
    f32x4 acc[2][6];  // ni 0,1=q  2,3=k  4,5=v
#pragma unroll
    for (int mi = 0; mi < 2; ++mi)
#pragma unroll
        for (int ni = 0; ni < 6; ++ni) acc[mi][ni] = (f32x4){0.f, 0.f, 0.f, 0.f};

#pragma unroll 2
    for (int ks = 0; ks < 8; ++ks) {
        const int kb = ks * 32;
        bf16x8 ahi[2], alo[2];
#pragma unroll
        for (int mi = 0; mi < 2; ++mi) {
            int row = w * 32 + mi * 16 + l15;
            size_t off = xbase + row * CDIM + kb + sct * 8;
            ahi[mi] = *reinterpret_cast<const bf16x8*>(XHi + off);
            alo[mi] = *reinterpret_cast<const bf16x8*>(XLo + off);
        }
#pragma unroll
        for (int ni = 0; ni < 6; ++ni) {
            int j = ((ni >> 1) << 8) + h * HD + ((ni & 1) << 4) + l15;
            const int woff = j * 256 + kb + sct * 8;
            bf16x8 bh = *reinterpret_cast<const bf16x8*>(WtHi + woff);
            if (ni < 4) {
                bf16x8 bl = *reinterpret_cast<const bf16x8*>(WtLo + woff);
#pragma unroll
                for (int mi = 0; mi < 2; ++mi) {
                    acc[mi][ni] = __builtin_amdgcn_mfma_f32_16x16x32_bf16(ahi[mi], bh, acc[mi][ni], 0, 0, 0);
                    acc[mi][ni] = __builtin_amdgcn_mfma_f32_16x16x32_bf16(ahi[mi], bl, acc[mi][ni], 0, 0, 0);
                    acc[mi][ni] = __builtin_amdgcn_mfma_f32_16x16x32_bf16(alo[mi], bh, acc[mi][ni], 0, 0, 0);
                }
            } else {  // v: bf16 precision is enough
#pragma unroll
                for (int mi = 0; mi < 2; ++mi)
                    acc[mi][ni] = __builtin_amdgcn_mfma_f32_16x16x32_bf16(ahi[mi], bh, acc[mi][ni], 0, 0, 0);
            }
        }
    }
    // epilogue: bias (+scale for q), split q/k, bf16 v
#pragma unroll
    for (int ni = 0; ni < 6; ++ni) {
        const int sel = ni >> 1;
        const int dcol = ((ni & 1) << 4) + l15;
        const float bias = BIAS[(sel << 8) + h * HD + dcol];
#pragma unroll
        for (int mi = 0; mi < 2; ++mi) {
            const int tb = w * 32 + mi * 16 + sct * 4;
            if (sel == 2) {
                float v0 = acc[mi][ni][0] + bias, v1 = acc[mi][ni][1] + bias;
                float v2 = acc[mi][ni][2] + bias, v3 = acc[mi][ni][3] + bias;
                unsigned pA = pk_bf16(v0, v1), pB = pk_bf16(v2, v3);
                int c0i = tb ^ ((dcol & 7) << 3);
                *reinterpret_cast<uint2*>(&vh[dcol * SEQN + c0i]) = make_uint2(pA, pB);
            } else {
                unsigned short* ph = sel ? kh : qh;
                unsigned short* pl = sel ? kl : ql;
#pragma unroll
                for (int r = 0; r < 4; ++r) {
                    float v = acc[mi][ni][r] + bias;
                    if (sel == 0) v *= scale;
                    unsigned short hi = bf16_rn(v);
                    int token = tb + r;
                    int idx = token * HD + (dcol ^ (((token >> 1) & 3) << 3));
                    ph[idx] = hi;
                    pl[idx] = bf16_rn(v - bf16f(hi));
                }
            }
        }
    }
    __syncthreads();

    // ================= Phase 2: S^T = K·Q^T, in-register softmax ============
    f32x4 sacc[8][2];
#pragma unroll
    for (int mi = 0; mi < 8; ++mi)
#pragma unroll
        for (int ni = 0; ni < 2; ++ni) sacc[mi][ni] = (f32x4){0.f, 0.f, 0.f, 0.f};

    bf16x8 qfh[2], qfl[2];
#pragma unroll
    for (int ni = 0; ni < 2; ++ni) {
        int qrow = w * 32 + (ni << 4) + l15;
        int off = qrow * HD + ((sct * 8) ^ (((qrow >> 1) & 3) << 3));
        qfh[ni] = *reinterpret_cast<const bf16x8*>(qh + off);
        qfl[ni] = *reinterpret_cast<const bf16x8*>(ql + off);
    }
#pragma unroll
    for (int mi = 0; mi < 8; ++mi) {
        int krow = (mi << 4) + l15;
        int off = krow * HD + ((sct * 8) ^ (((krow >> 1) & 3) << 3));
        bf16x8 kfh = *reinterpret_cast<const bf16x8*>(kh + off);
        bf16x8 kfl = *reinterpret_cast<const bf16x8*>(kl + off);
#pragma unroll
        for (int ni = 0; ni < 2; ++ni) {
            sacc[mi][ni] = __builtin_amdgcn_mfma_f32_16x16x32_bf16(kfh, qfh[ni], sacc[mi][ni], 0, 0, 0);
            sacc[mi][ni] = __builtin_amdgcn_mfma_f32_16x16x32_bf16(kfh, qfl[ni], sacc[mi][ni], 0, 0, 0);
            sacc[mi][ni] = __builtin_amdgcn_mfma_f32_16x16x32_bf16(kfl, qfh[ni], sacc[mi][ni], 0, 0, 0);
        }
    }
    // ordered keys in place
#pragma unroll
    for (int mi = 0; mi < 8; ++mi)
#pragma unroll
        for (int ni = 0; ni < 2; ++ni)
#pragma unroll
            for (int r = 0; r < 4; ++r)
                sacc[mi][ni][r] = __uint_as_float(okey(sacc[mi][ni][r]));

    // exact top-20 threshold per q-row (radix select over 4 lanes)
    unsigned int p0 = 0u, p1 = 0u;
    for (int bit = 31; bit >= 0; --bit) {
        unsigned int t0 = p0 | (1u << bit), t1 = p1 | (1u << bit);
        int c0 = 0, c1 = 0;
#pragma unroll
        for (int mi = 0; mi < 8; ++mi)
#pragma unroll
            for (int r = 0; r < 4; ++r) {
                c0 += (__float_as_uint(sacc[mi][0][r]) >= t0) ? 1 : 0;
                c1 += (__float_as_uint(sacc[mi][1][r]) >= t1) ? 1 : 0;
            }
        int m = c0 | (c1 << 8);
        m += __shfl_xor(m, 16);
        m += __shfl_xor(m, 32);
        if ((m & 255) >= TOPM) p0 = t0;
        if ((m >> 8) >= TOPM) p1 = t1;
    }
    // row max (monotone in key domain)
    unsigned int km0 = 0u, km1 = 0u;
#pragma unroll
    for (int mi = 0; mi < 8; ++mi)
#pragma unroll
        for (int r = 0; r < 4; ++r) {
            km0 = max(km0, __float_as_uint(sacc[mi][0][r]));
            km1 = max(km1, __float_as_uint(sacc[mi][1][r]));
        }
    km0 = max(km0, (unsigned int)__shfl_xor((int)km0, 16));
    km0 = max(km0, (unsigned int)__shfl_xor((int)km0, 32));
    km1 = max(km1, (unsigned int)__shfl_xor((int)km1, 16));
    km1 = max(km1, (unsigned int)__shfl_xor((int)km1, 32));
    float mx0 = okey_inv(km0), mx1 = okey_inv(km1);

    // masked exp (unnormalized) in place + row sums
    float s0 = 0.f, s1 = 0.f;
#pragma unroll
    for (int mi = 0; mi < 8; ++mi)
#pragma unroll
        for (int r = 0; r < 4; ++r) {
            unsigned int u0 = __float_as_uint(sacc[mi][0][r]);
            unsigned int u1 = __float_as_uint(sacc[mi][1][r]);
            float e0 = (u0 >= p0) ? __expf(okey_inv(u0) - mx0) : 0.f;
            float e1 = (u1 >= p1) ? __expf(okey_inv(u1) - mx1) : 0.f;
            sacc[mi][0][r] = e0;
            sacc[mi][1][r] = e1;
            s0 += e0;
            s1 += e1;
        }
    s0 += __shfl_xor(s0, 16);
    s0 += __shfl_xor(s0, 32);
    s1 += __shfl_xor(s1, 16);
    s1 += __shfl_xor(s1, 32);
    float i0 = 1.f / s0, i1 = 1.f / s1;

    // pack weights to bf16 pairs: w16[mi][ni][p] = (r=2p, r=2p+1)
    unsigned w16[8][2][2];
#pragma unroll
    for (int mi = 0; mi < 8; ++mi)
#pragma unroll
        for (int ni = 0; ni < 2; ++ni)
#pragma unroll
            for (int p = 0; p < 2; ++p)
                w16[mi][ni][p] = pk_bf16(sacc[mi][ni][2 * p], sacc[mi][ni][2 * p + 1]);

    // ================= Phase 3: O = P·V via MFMA (single bf16) ==============
    f32x4 oacc[2][2];
#pragma unroll
    for (int mi = 0; mi < 2; ++mi)
#pragma unroll
        for (int ni = 0; ni < 2; ++ni) oacc[mi][ni] = (f32x4){0.f, 0.f, 0.f, 0.f};

#pragma unroll
    for (int k = 0; k < 4; ++k) {
        bf16x8 bvh[2];
#pragma unroll
        for (int nio = 0; nio < 2; ++nio) {
            int drow = (nio << 4) + l15;
            int off = drow * SEQN + ((k * 32 + sct * 8) ^ ((drow & 7) << 3));
            bvh[nio] = *reinterpret_cast<const bf16x8*>(vh + off);
        }
#pragma unroll
        for (int mio = 0; mio < 2; ++mio) {
            union { unsigned u[4]; bf16x8 v8; } aw;
#pragma unroll
            for (int j = 0; j < 4; ++j) {
                int src = l15 + ((sct & 1) << 5) + ((j >> 1) << 4);
                unsigned a0 = (unsigned)__shfl((int)w16[2 * k][mio][j & 1], src);
                unsigned a1 = (unsigned)__shfl((int)w16[2 * k + 1][mio][j & 1], src);
                aw.u[j] = (sct >= 2) ? a1 : a0;
            }
#pragma unroll
            for (int nio = 0; nio < 2; ++nio)
                oacc[mio][nio] = __builtin_amdgcn_mfma_f32_16x16x32_bf16(aw.v8, bvh[nio], oacc[mio][nio], 0, 0, 0);
        }
    }
    // per-output-row 1/sum, then store
    float invO[2][4];
#pragma unroll
    for (int mio = 0; mio < 2; ++mio)
#pragma unroll
        for (int r = 0; r < 4; ++r)
            invO[mio][r] = __shfl(mio ? i1 : i0, sct * 4 + r);
#pragma unroll
    for (int mio = 0; mio < 2; ++mio)
#pragma unroll
        for (int nio = 0; nio < 2; ++nio)
#pragma unroll
            for (int r = 0; r < 4; ++r) {
                int token = w * 32 + mio * 16 + sct * 4 + r;
                int d = (nio << 4) + l15;
                O[((size_t)b * SEQN + token) * CDIM + h * HD + d] = oacc[mio][nio][r] * invO[mio][r];
            }
}

// ---------------------------------------------------------------------------
// K3: proj GEMM + bias + residual(from planes) + LayerNorm -> new planes.
__global__ __launch_bounds__(256) void projln_kernel(const float* __restrict__ O,
                                                     unsigned short* __restrict__ XH,
                                                     unsigned short* __restrict__ XL,
                                                     const float* __restrict__ W,
                                                     const float* __restrict__ PB,
                                                     const float* __restrict__ G,
                                                     const float* __restrict__ BB) {
    int b = blockIdx.x;
    int t0 = blockIdx.y * 16;
    __shared__ float T[16 * 256];
    __shared__ float red[2][16][16];
    __shared__ float mstat[16], rstdv[16];
    int tid = threadIdx.x;

#pragma unroll
    for (int ii = 0; ii < 16; ++ii) {
        int e = tid + 256 * ii;
        T[e] = O[((size_t)b * SEQN + t0 + (e >> 8)) * CDIM + (e & 255)];
    }
    __syncthreads();

    int j = tid;
    float acc[16];
#pragma unroll
    for (int i = 0; i < 16; ++i) acc[i] = 0.f;
    for (int k = 0; k < CDIM; ++k) {
        float w = W[k * CDIM + j];
#pragma unroll
        for (int i = 0; i < 16; ++i) acc[i] = fmaf(T[i * 256 + k], w, acc[i]);
    }
    float bias = PB[j];
    float vals[16];
#pragma unroll
    for (int i = 0; i < 16; ++i) {
        size_t idx = ((size_t)b * SEQN + t0 + i) * CDIM + j;
        float res = bf16f(XH[idx]) + bf16f(XL[idx]);
        vals[i] = acc[i] + bias + res;
    }
    __syncthreads();
#pragma unroll
    for (int i = 0; i < 16; ++i) T[i * 256 + j] = vals[i];
    __syncthreads();
    {
        int i2 = tid >> 4, sidx = tid & 15;
        float ps = 0.f, pq = 0.f;
#pragma unroll
        for (int t = 0; t < 16; ++t) {
            float u = T[i2 * 256 + sidx * 16 + t];
            ps += u;
            pq += u * u;
        }
        red[0][i2][sidx] = ps;
        red[1][i2][sidx] = pq;
    }
    __syncthreads();
    if (tid < 16) {
        float s1 = 0.f, s2 = 0.f;
#pragma unroll
        for (int t = 0; t < 16; ++t) { s1 += red[0][tid][t]; s2 += red[1][tid][t]; }
        float m = s1 * (1.f / 256.f);
        float var = s2 * (1.f / 256.f) - m * m;
        mstat[tid] = m;
        rstdv[tid] = rsqrtf(var + 1e-5f);
    }
    __syncthreads();
    float gj = G[j], bj = BB[j];
#pragma unroll
    for (int i = 0; i < 16; ++i) {
        float y = (vals[i] - mstat[i]) * rstdv[i] * gj + bj;
        size_t idx = ((size_t)b * SEQN + t0 + i) * CDIM + j;
        unsigned short hi = bf16_rn(y);
        XH[idx] = hi;
        XL[idx] = bf16_rn(y - bf16f(hi));
    }
}

// ---------------------------------------------------------------------------
// K4: mean over tokens + classifier head (reads planes). grid 480, block 256.
__global__ __launch_bounds__(256) void cls_kernel(const unsigned short* __restrict__ XH,
                                                  const unsigned short* __restrict__ XL,
                                                  const float* __restrict__ W1,
                                                  const float* __restrict__ B1,
                                                  const float* __restrict__ W2,
                                                  const float* __restrict__ B2,
                                                  float* __restrict__ OUT) {
    int b = blockIdx.x;
    __shared__ float xm[256];
    __shared__ float hred[128];
    int tid = threadIdx.x;
    float sm = 0.f;
    for (int n = 0; n < SEQN; ++n) {
        size_t idx = ((size_t)b * SEQN + n) * CDIM + tid;
        sm += bf16f(XH[idx]) + bf16f(XL[idx]);
    }
    xm[tid] = sm * (1.f / 128.f);
    __syncthreads();
    if (tid < 128) {
        float a = B1[tid];
        for (int k = 0; k < CDIM; ++k) a = fmaf(xm[k], W1[k * 128 + tid], a);
        a = fmaxf(a, 0.f);
        hred[tid] = a * W2[tid];
    }
    __syncthreads();
    for (int off = 64; off > 0; off >>= 1) {
        if (tid < off) hred[tid] += hred[tid + off];
        __syncthreads();
    }
    if (tid == 0) OUT[b] = hred[0] + B2[0];
}

// ---------------------------------------------------------------------------
extern "C" void kernel_launch(void* const* d_in, const int* in_sizes, int n_in,
                              void* d_out, int out_size, void* d_ws, size_t ws_size,
                              hipStream_t stream) {
    const float* RW  = (const float*)d_in[0];
    const float* POS = (const float*)d_in[1];
    const float* CW1 = (const float*)d_in[2];
    const float* CB1 = (const float*)d_in[3];
    const float* CW2 = (const float*)d_in[4];
    const float* CB2 = (const float*)d_in[5];

    const size_t NTOK = (size_t)NSEQ * SEQN * CDIM;  // 15.7M
    float* O = (float*)d_ws;                          // 63 MB
    unsigned short* XH = (unsigned short*)(O + NTOK); // 31.5 MB
    unsigned short* XL = XH + NTOK;                   // 31.5 MB
    unsigned short* WtHi = XL + NTOK;                 // 0.39 MB
    unsigned short* WtLo = WtHi + (size_t)768 * 256;  // 0.39 MB

    prep_kernel<<<dim3(NSEQ, 4, 8), 256, 0, stream>>>(RW, POS, XH, XL);

    for (int li = 0; li < 2; ++li) {
        const float* qw = (const float*)d_in[6 + 6 * li];
        const float* qb = (const float*)d_in[7 + 6 * li];
        const float* pw = (const float*)d_in[8 + 6 * li];
        const float* pb = (const float*)d_in[9 + 6 * li];
        const float* lg = (const float*)d_in[10 + 6 * li];
        const float* lb = (const float*)d_in[11 + 6 * li];
        wsplit_kernel<<<dim3(8, 24), 256, 0, stream>>>(qw, WtHi, WtLo);
        attn_kernel<<<NSEQ * NH, 256, 0, stream>>>(XH, XL, O, WtHi, WtLo, qb);
        projln_kernel<<<dim3(NSEQ, 8), 256, 0, stream>>>(O, XH, XL, pw, pb, lg, lb);
    }

    cls_kernel<<<NSEQ, 256, 0, stream>>>(XH, XL, CW1, CB1, CW2, CB2, (float*)d_out);
}

// Round 5
// 787.800 us; speedup vs baseline: 5.4172x; 1.0921x over previous
//
#include <hip/hip_runtime.h>
#include <hip/hip_bf16.h>
#include <cmath>

#define NSEQ 480
#define SEQN 128
#define CDIM 256
#define NH 8
#define HD 32
#define TOPM 20

typedef float f32x4 __attribute__((ext_vector_type(4)));
typedef short bf16x8 __attribute__((ext_vector_type(8)));

__device__ __forceinline__ unsigned short bf16_rn(float x) {
    unsigned int u = __float_as_uint(x);
    unsigned int r = (u + 0x7FFFu + ((u >> 16) & 1u)) >> 16;
    return (unsigned short)r;
}
__device__ __forceinline__ float bf16f(unsigned short h) {
    return __uint_as_float(((unsigned int)h) << 16);
}
__device__ __forceinline__ unsigned int okey(float v) {
    unsigned int u = __float_as_uint(v);
    return (u >> 31) ? ~u : (u | 0x80000000u);
}
__device__ __forceinline__ float okey_inv(unsigned int k) {
    return __uint_as_float((k >> 31) ? (k & 0x7FFFFFFFu) : ~k);
}
__device__ __forceinline__ unsigned pk_bf16(float a, float b) {
    union { __hip_bfloat162 h; unsigned u; } cv;
    cv.h = __float22bfloat162_rn(make_float2(a, b));
    return cv.u;
}
__device__ __forceinline__ void unpack_bf16x8(uint4 u, float* o) {
    o[0] = bf16f((unsigned short)(u.x & 0xffffu)); o[1] = bf16f((unsigned short)(u.x >> 16));
    o[2] = bf16f((unsigned short)(u.y & 0xffffu)); o[3] = bf16f((unsigned short)(u.y >> 16));
    o[4] = bf16f((unsigned short)(u.z & 0xffffu)); o[5] = bf16f((unsigned short)(u.z >> 16));
    o[6] = bf16f((unsigned short)(u.w & 0xffffu)); o[7] = bf16f((unsigned short)(u.w >> 16));
}

// ---------------------------------------------------------------------------
// K1: transpose (B, C, N) -> (B, N, C), add pos_embed, emit split-bf16 planes
__global__ __launch_bounds__(256) void prep_kernel(const float* __restrict__ RW,
                                                   const float* __restrict__ POS,
                                                   unsigned short* __restrict__ XH,
                                                   unsigned short* __restrict__ XL) {
    int b = blockIdx.x, n0 = blockIdx.y * 32, c0 = blockIdx.z * 32;
    __shared__ float tile[32][33];
    int tx = threadIdx.x & 31, ty = threadIdx.x >> 5;
#pragma unroll
    for (int jj = 0; jj < 4; ++jj) {
        int c = c0 + ty + 8 * jj;
        tile[ty + 8 * jj][tx] = RW[((size_t)b * CDIM + c) * SEQN + n0 + tx];
    }
    __syncthreads();
#pragma unroll
    for (int jj = 0; jj < 4; ++jj) {
        int n = n0 + ty + 8 * jj;
        int c = c0 + tx;
        float val = tile[tx][ty + 8 * jj] + POS[n * CDIM + c];
        unsigned short hi = bf16_rn(val);
        size_t idx = (size_t)b * SEQN * CDIM + n * CDIM + c;
        XH[idx] = hi;
        XL[idx] = bf16_rn(val - bf16f(hi));
    }
}

// ---------------------------------------------------------------------------
// K1b: W (256, ncols) -> Wt_hi/Wt_lo [ncols][256] bf16 split.  grid (8, ncols/32).
__global__ __launch_bounds__(256) void wsplit_kernel(const float* __restrict__ W,
                                                     unsigned short* __restrict__ WtHi,
                                                     unsigned short* __restrict__ WtLo,
                                                     int ncols) {
    int k0 = blockIdx.x * 32, j0 = blockIdx.y * 32;
    __shared__ float tile[32][33];
    int tx = threadIdx.x & 31, ty = threadIdx.x >> 5;
#pragma unroll
    for (int jj = 0; jj < 4; ++jj)
        tile[ty + 8 * jj][tx] = W[(size_t)(k0 + ty + 8 * jj) * ncols + j0 + tx];
    __syncthreads();
#pragma unroll
    for (int jj = 0; jj < 4; ++jj) {
        float v = tile[tx][ty + 8 * jj];
        unsigned short hi = bf16_rn(v);
        unsigned short lo = bf16_rn(v - bf16f(hi));
        size_t idx = (size_t)(j0 + ty + 8 * jj) * 256 + k0 + tx;
        WtHi[idx] = hi;
        WtLo[idx] = lo;
    }
}

// ---------------------------------------------------------------------------
// K2: fused qkv + exact top-20 attention.  Q/K split-bf16 (3-term MFMA),
// V and P single-bf16.  Selection = bracketed bisection w/ early exit.
// grid 3840, bid = (b&7) + 8h + 64(b>>3).  block 256.  LDS = 40 KiB.
__global__ __launch_bounds__(256, 4) void attn_kernel(
    const unsigned short* __restrict__ XHi, const unsigned short* __restrict__ XLo,
    unsigned short* __restrict__ OH, unsigned short* __restrict__ OL,
    const unsigned short* __restrict__ WtHi, const unsigned short* __restrict__ WtLo,
    const float* __restrict__ BIAS) {
    const int bid = blockIdx.x;
    const int h = (bid >> 3) & 7;
    const int b = ((bid >> 6) << 3) | (bid & 7);
    const float scale = 0.17677669529663687f;  // 1/sqrt(32)

    __shared__ unsigned short qh[SEQN * HD], ql[SEQN * HD];
    __shared__ unsigned short kh[SEQN * HD], kl[SEQN * HD];
    __shared__ unsigned short vh[HD * SEQN];

    const int tid = threadIdx.x;
    const int w = tid >> 6;
    const int l = tid & 63;
    const int l15 = l & 15;
    const int sct = l >> 4;
    const size_t xbase = (size_t)b * SEQN * CDIM;

    // ================= Phase 1: QKV via MFMA =================
    f32x4 acc[2][6];  // ni 0,1=q  2,3=k  4,5=v
#pragma unroll
    for (int mi = 0; mi < 2; ++mi)
#pragma unroll
        for (int ni = 0; ni < 6; ++ni) acc[mi][ni] = (f32x4){0.f, 0.f, 0.f, 0.f};

#pragma unroll 2
    for (int ks = 0; ks < 8; ++ks) {
        const int kb = ks * 32;
        bf16x8 ahi[2], alo[2];
#pragma unroll
        for (int mi = 0; mi < 2; ++mi) {
            int row = w * 32 + mi * 16 + l15;
            size_t off = xbase + row * CDIM + kb + sct * 8;
            ahi[mi] = *reinterpret_cast<const bf16x8*>(XHi + off);
            alo[mi] = *reinterpret_cast<const bf16x8*>(XLo + off);
        }
#pragma unroll
        for (int ni = 0; ni < 6; ++ni) {
            int j = ((ni >> 1) << 8) + h * HD + ((ni & 1) << 4) + l15;
            const int woff = j * 256 + kb + sct * 8;
            bf16x8 bh = *reinterpret_cast<const bf16x8*>(WtHi + woff);
            if (ni < 4) {
                bf16x8 bl = *reinterpret_cast<const bf16x8*>(WtLo + woff);
#pragma unroll
                for (int mi = 0; mi < 2; ++mi) {
                    acc[mi][ni] = __builtin_amdgcn_mfma_f32_16x16x32_bf16(ahi[mi], bh, acc[mi][ni], 0, 0, 0);
                    acc[mi][ni] = __builtin_amdgcn_mfma_f32_16x16x32_bf16(ahi[mi], bl, acc[mi][ni], 0, 0, 0);
                    acc[mi][ni] = __builtin_amdgcn_mfma_f32_16x16x32_bf16(alo[mi], bh, acc[mi][ni], 0, 0, 0);
                }
            } else {
#pragma unroll
                for (int mi = 0; mi < 2; ++mi)
                    acc[mi][ni] = __builtin_amdgcn_mfma_f32_16x16x32_bf16(ahi[mi], bh, acc[mi][ni], 0, 0, 0);
            }
        }
    }
#pragma unroll
    for (int ni = 0; ni < 6; ++ni) {
        const int sel = ni >> 1;
        const int dcol = ((ni & 1) << 4) + l15;
        const float bias = BIAS[(sel << 8) + h * HD + dcol];
#pragma unroll
        for (int mi = 0; mi < 2; ++mi) {
            const int tb = w * 32 + mi * 16 + sct * 4;
            if (sel == 2) {
                float v0 = acc[mi][ni][0] + bias, v1 = acc[mi][ni][1] + bias;
                float v2 = acc[mi][ni][2] + bias, v3 = acc[mi][ni][3] + bias;
                unsigned pA = pk_bf16(v0, v1), pB = pk_bf16(v2, v3);
                int c0i = tb ^ ((dcol & 7) << 3);
                *reinterpret_cast<uint2*>(&vh[dcol * SEQN + c0i]) = make_uint2(pA, pB);
            } else {
                unsigned short* ph = sel ? kh : qh;
                unsigned short* pl = sel ? kl : ql;
#pragma unroll
                for (int r = 0; r < 4; ++r) {
                    float v = acc[mi][ni][r] + bias;
                    if (sel == 0) v *= scale;
                    unsigned short hi = bf16_rn(v);
                    int token = tb + r;
                    int idx = token * HD + (dcol ^ (((token >> 1) & 3) << 3));
                    ph[idx] = hi;
                    pl[idx] = bf16_rn(v - bf16f(hi));
                }
            }
        }
    }
    __syncthreads();

    // ================= Phase 2: S^T = K·Q^T, in-register softmax ============
    f32x4 sacc[8][2];
#pragma unroll
    for (int mi = 0; mi < 8; ++mi)
#pragma unroll
        for (int ni = 0; ni < 2; ++ni) sacc[mi][ni] = (f32x4){0.f, 0.f, 0.f, 0.f};

    bf16x8 qfh[2], qfl[2];
#pragma unroll
    for (int ni = 0; ni < 2; ++ni) {
        int qrow = w * 32 + (ni << 4) + l15;
        int off = qrow * HD + ((sct * 8) ^ (((qrow >> 1) & 3) << 3));
        qfh[ni] = *reinterpret_cast<const bf16x8*>(qh + off);
        qfl[ni] = *reinterpret_cast<const bf16x8*>(ql + off);
    }
#pragma unroll
    for (int mi = 0; mi < 8; ++mi) {
        int krow = (mi << 4) + l15;
        int off = krow * HD + ((sct * 8) ^ (((krow >> 1) & 3) << 3));
        bf16x8 kfh = *reinterpret_cast<const bf16x8*>(kh + off);
        bf16x8 kfl = *reinterpret_cast<const bf16x8*>(kl + off);
#pragma unroll
        for (int ni = 0; ni < 2; ++ni) {
            sacc[mi][ni] = __builtin_amdgcn_mfma_f32_16x16x32_bf16(kfh, qfh[ni], sacc[mi][ni], 0, 0, 0);
            sacc[mi][ni] = __builtin_amdgcn_mfma_f32_16x16x32_bf16(kfh, qfl[ni], sacc[mi][ni], 0, 0, 0);
            sacc[mi][ni] = __builtin_amdgcn_mfma_f32_16x16x32_bf16(kfl, qfh[ni], sacc[mi][ni], 0, 0, 0);
        }
    }
    // convert to ordered keys in place
#pragma unroll
    for (int mi = 0; mi < 8; ++mi)
#pragma unroll
        for (int ni = 0; ni < 2; ++ni)
#pragma unroll
            for (int r = 0; r < 4; ++r)
                sacc[mi][ni][r] = __uint_as_float(okey(sacc[mi][ni][r]));

    // row max (monotone in key domain)
    unsigned int km0 = 0u, km1 = 0u;
#pragma unroll
    for (int mi = 0; mi < 8; ++mi)
#pragma unroll
        for (int r = 0; r < 4; ++r) {
            km0 = max(km0, __float_as_uint(sacc[mi][0][r]));
            km1 = max(km1, __float_as_uint(sacc[mi][1][r]));
        }
    km0 = max(km0, (unsigned int)__shfl_xor((int)km0, 16));
    km0 = max(km0, (unsigned int)__shfl_xor((int)km0, 32));
    km1 = max(km1, (unsigned int)__shfl_xor((int)km1, 16));
    km1 = max(km1, (unsigned int)__shfl_xor((int)km1, 32));
    float mx0 = okey_inv(km0), mx1 = okey_inv(km1);

    // exact top-20 threshold per q-row: bracketed bisection, early exit at c==20
    unsigned p0, p1;
    {
        unsigned lo0 = 0u, hi0 = km0 + 1u, lo1 = 0u, hi1 = km1 + 1u;
        unsigned th0 = km0, th1 = km1;
        int dn0 = 0, dn1 = 0;
#pragma unroll 1
        for (int it = 0; it < 34; ++it) {
            if (__all(dn0 & dn1)) break;
            unsigned mid0 = lo0 + ((hi0 - lo0) >> 1);
            unsigned mid1 = lo1 + ((hi1 - lo1) >> 1);
            int c0 = 0, c1 = 0;
#pragma unroll
            for (int mi = 0; mi < 8; ++mi)
#pragma unroll
                for (int r = 0; r < 4; ++r) {
                    c0 += (__float_as_uint(sacc[mi][0][r]) >= mid0) ? 1 : 0;
                    c1 += (__float_as_uint(sacc[mi][1][r]) >= mid1) ? 1 : 0;
                }
            int mpk = c0 | (c1 << 8);
            mpk += __shfl_xor(mpk, 16);
            mpk += __shfl_xor(mpk, 32);
            c0 = mpk & 255;
            c1 = mpk >> 8;
            if (!dn0) {
                if (c0 == TOPM) { th0 = mid0; dn0 = 1; }
                else if (hi0 - lo0 <= 1u) { th0 = lo0; dn0 = 1; }
                else if (c0 > TOPM) lo0 = mid0;
                else hi0 = mid0;
            }
            if (!dn1) {
                if (c1 == TOPM) { th1 = mid1; dn1 = 1; }
                else if (hi1 - lo1 <= 1u) { th1 = lo1; dn1 = 1; }
                else if (c1 > TOPM) lo1 = mid1;
                else hi1 = mid1;
            }
        }
        p0 = th0; p1 = th1;
    }

    // masked exp (unnormalized) + row sums
    float s0 = 0.f, s1 = 0.f;
#pragma unroll
    for (int mi = 0; mi < 8; ++mi)
#pragma unroll
        for (int r = 0; r < 4; ++r) {
            unsigned int u0 = __float_as_uint(sacc[mi][0][r]);
            unsigned int u1 = __float_as_uint(sacc[mi][1][r]);
            float e0 = (u0 >= p0) ? __expf(okey_inv(u0) - mx0) : 0.f;
            float e1 = (u1 >= p1) ? __expf(okey_inv(u1) - mx1) : 0.f;
            sacc[mi][0][r] = e0;
            sacc[mi][1][r] = e1;
            s0 += e0;
            s1 += e1;
        }
    s0 += __shfl_xor(s0, 16);
    s0 += __shfl_xor(s0, 32);
    s1 += __shfl_xor(s1, 16);
    s1 += __shfl_xor(s1, 32);
    float i0 = 1.f / s0, i1 = 1.f / s1;

    unsigned w16[8][2][2];
#pragma unroll
    for (int mi = 0; mi < 8; ++mi)
#pragma unroll
        for (int ni = 0; ni < 2; ++ni)
#pragma unroll
            for (int p = 0; p < 2; ++p)
                w16[mi][ni][p] = pk_bf16(sacc[mi][ni][2 * p], sacc[mi][ni][2 * p + 1]);

    // ================= Phase 3: O = P·V via MFMA ==============
    f32x4 oacc[2][2];
#pragma unroll
    for (int mi = 0; mi < 2; ++mi)
#pragma unroll
        for (int ni = 0; ni < 2; ++ni) oacc[mi][ni] = (f32x4){0.f, 0.f, 0.f, 0.f};

#pragma unroll
    for (int k = 0; k < 4; ++k) {
        bf16x8 bvh[2];
#pragma unroll
        for (int nio = 0; nio < 2; ++nio) {
            int drow = (nio << 4) + l15;
            int off = drow * SEQN + ((k * 32 + sct * 8) ^ ((drow & 7) << 3));
            bvh[nio] = *reinterpret_cast<const bf16x8*>(vh + off);
        }
#pragma unroll
        for (int mio = 0; mio < 2; ++mio) {
            union { unsigned u[4]; bf16x8 v8; } aw;
#pragma unroll
            for (int j = 0; j < 4; ++j) {
                int src = l15 + ((sct & 1) << 5) + ((j >> 1) << 4);
                unsigned a0 = (unsigned)__shfl((int)w16[2 * k][mio][j & 1], src);
                unsigned a1 = (unsigned)__shfl((int)w16[2 * k + 1][mio][j & 1], src);
                aw.u[j] = (sct >= 2) ? a1 : a0;
            }
#pragma unroll
            for (int nio = 0; nio < 2; ++nio)
                oacc[mio][nio] = __builtin_amdgcn_mfma_f32_16x16x32_bf16(aw.v8, bvh[nio], oacc[mio][nio], 0, 0, 0);
        }
    }
    float invO[2][4];
#pragma unroll
    for (int mio = 0; mio < 2; ++mio)
#pragma unroll
        for (int r = 0; r < 4; ++r)
            invO[mio][r] = __shfl(mio ? i1 : i0, sct * 4 + r);
#pragma unroll
    for (int mio = 0; mio < 2; ++mio)
#pragma unroll
        for (int nio = 0; nio < 2; ++nio)
#pragma unroll
            for (int r = 0; r < 4; ++r) {
                int token = w * 32 + mio * 16 + sct * 4 + r;
                int d = (nio << 4) + l15;
                size_t idx = ((size_t)b * SEQN + token) * CDIM + h * HD + d;
                float v = oacc[mio][nio][r] * invO[mio][r];
                unsigned short hi = bf16_rn(v);
                OH[idx] = hi;
                OL[idx] = bf16_rn(v - bf16f(hi));
            }
}

// ---------------------------------------------------------------------------
// K3: MFMA proj GEMM + bias + residual + LayerNorm, 32 tokens per block.
// grid (480, 4), block 256 (4 waves, each 32 tok x 64 cols).  LDS ~39 KB.
__global__ __launch_bounds__(256, 4) void projln_kernel(
    const unsigned short* __restrict__ OHp, const unsigned short* __restrict__ OLp,
    unsigned short* __restrict__ XH, unsigned short* __restrict__ XL,
    const unsigned short* __restrict__ W2H, const unsigned short* __restrict__ W2L,
    const float* __restrict__ PB, const float* __restrict__ G,
    const float* __restrict__ BB) {
    const int b = blockIdx.x;
    const int t0 = blockIdx.y * 32;
    __shared__ float vals[32 * 289];
    __shared__ float part[8][32][2];

    const int tid = threadIdx.x;
    const int w = tid >> 6;
    const int l = tid & 63;
    const int l15 = l & 15;
    const int sct = l >> 4;

    f32x4 acc[2][4];
#pragma unroll
    for (int mi = 0; mi < 2; ++mi)
#pragma unroll
        for (int ni = 0; ni < 4; ++ni) acc[mi][ni] = (f32x4){0.f, 0.f, 0.f, 0.f};

    const size_t obase = ((size_t)b * SEQN + t0) * CDIM;
#pragma unroll 2
    for (int ks = 0; ks < 8; ++ks) {
        const int kb = ks * 32;
        bf16x8 ahi[2], alo[2];
#pragma unroll
        for (int mi = 0; mi < 2; ++mi) {
            size_t off = obase + (size_t)(mi * 16 + l15) * CDIM + kb + sct * 8;
            ahi[mi] = *reinterpret_cast<const bf16x8*>(OHp + off);
            alo[mi] = *reinterpret_cast<const bf16x8*>(OLp + off);
        }
#pragma unroll
        for (int ni = 0; ni < 4; ++ni) {
            int j = w * 64 + ni * 16 + l15;
            int woff = j * 256 + kb + sct * 8;
            bf16x8 bh = *reinterpret_cast<const bf16x8*>(W2H + woff);
            bf16x8 bl = *reinterpret_cast<const bf16x8*>(W2L + woff);
#pragma unroll
            for (int mi = 0; mi < 2; ++mi) {
                acc[mi][ni] = __builtin_amdgcn_mfma_f32_16x16x32_bf16(ahi[mi], bh, acc[mi][ni], 0, 0, 0);
                acc[mi][ni] = __builtin_amdgcn_mfma_f32_16x16x32_bf16(ahi[mi], bl, acc[mi][ni], 0, 0, 0);
                acc[mi][ni] = __builtin_amdgcn_mfma_f32_16x16x32_bf16(alo[mi], bh, acc[mi][ni], 0, 0, 0);
            }
        }
    }
    // bias + stage to LDS (stride 289 -> conflict-free strided readback)
#pragma unroll
    for (int ni = 0; ni < 4; ++ni) {
        int j = w * 64 + ni * 16 + l15;
        float bias = PB[j];
#pragma unroll
        for (int mi = 0; mi < 2; ++mi)
#pragma unroll
            for (int r = 0; r < 4; ++r) {
                int tok = mi * 16 + sct * 4 + r;
                vals[tok * 289 + j] = acc[mi][ni][r] + bias;
            }
    }
    __syncthreads();

    // residual + stats: thread = (row 0..31, cc 0..7 chunks of 32 cols)
    const int row = tid & 31;
    const int cc = tid >> 5;
    const size_t rbase = ((size_t)b * SEQN + t0 + row) * CDIM + cc * 32;
    float v[32];
    {
        float ps = 0.f, pq = 0.f;
#pragma unroll
        for (int q = 0; q < 4; ++q) {
            uint4 hb = *reinterpret_cast<const uint4*>(XH + rbase + q * 8);
            uint4 lb = *reinterpret_cast<const uint4*>(XL + rbase + q * 8);
            float rh[8], rl[8];
            unpack_bf16x8(hb, rh);
            unpack_bf16x8(lb, rl);
#pragma unroll
            for (int jj = 0; jj < 8; ++jj) {
                int col = cc * 32 + q * 8 + jj;
                float val = vals[row * 289 + col] + rh[jj] + rl[jj];
                v[q * 8 + jj] = val;
                ps += val;
                pq = fmaf(val, val, pq);
            }
        }
        part[cc][row][0] = ps;
        part[cc][row][1] = pq;
    }
    __syncthreads();
    float s1 = 0.f, s2 = 0.f;
#pragma unroll
    for (int k = 0; k < 8; ++k) { s1 += part[k][row][0]; s2 += part[k][row][1]; }
    float m = s1 * (1.f / 256.f);
    float var = s2 * (1.f / 256.f) - m * m;
    float rstd = rsqrtf(var + 1e-5f);
#pragma unroll
    for (int q = 0; q < 4; ++q) {
        int col0 = cc * 32 + q * 8;
        float4 g0 = *reinterpret_cast<const float4*>(G + col0);
        float4 g1 = *reinterpret_cast<const float4*>(G + col0 + 4);
        float4 b0 = *reinterpret_cast<const float4*>(BB + col0);
        float4 b1 = *reinterpret_cast<const float4*>(BB + col0 + 4);
        float gg[8] = {g0.x, g0.y, g0.z, g0.w, g1.x, g1.y, g1.z, g1.w};
        float bb2[8] = {b0.x, b0.y, b0.z, b0.w, b1.x, b1.y, b1.z, b1.w};
        unsigned hw[4], lw[4];
#pragma unroll
        for (int p2 = 0; p2 < 4; ++p2) {
            float y0 = (v[q * 8 + p2 * 2] - m) * rstd * gg[p2 * 2] + bb2[p2 * 2];
            float y1 = (v[q * 8 + p2 * 2 + 1] - m) * rstd * gg[p2 * 2 + 1] + bb2[p2 * 2 + 1];
            unsigned short h0 = bf16_rn(y0), h1 = bf16_rn(y1);
            unsigned short lo0 = bf16_rn(y0 - bf16f(h0)), lo1 = bf16_rn(y1 - bf16f(h1));
            hw[p2] = (unsigned)h0 | ((unsigned)h1 << 16);
            lw[p2] = (unsigned)lo0 | ((unsigned)lo1 << 16);
        }
        *reinterpret_cast<uint4*>(XH + rbase + q * 8) = make_uint4(hw[0], hw[1], hw[2], hw[3]);
        *reinterpret_cast<uint4*>(XL + rbase + q * 8) = make_uint4(lw[0], lw[1], lw[2], lw[3]);
    }
}

// ---------------------------------------------------------------------------
// K4: mean over tokens + classifier head (reads planes). grid 480, block 256.
__global__ __launch_bounds__(256) void cls_kernel(const unsigned short* __restrict__ XH,
                                                  const unsigned short* __restrict__ XL,
                                                  const float* __restrict__ W1,
                                                  const float* __restrict__ B1,
                                                  const float* __restrict__ W2,
                                                  const float* __restrict__ B2,
                                                  float* __restrict__ OUT) {
    int b = blockIdx.x;
    __shared__ float xm[256];
    __shared__ float hred[128];
    int tid = threadIdx.x;
    float sm = 0.f;
    for (int n = 0; n < SEQN; ++n) {
        size_t idx = ((size_t)b * SEQN + n) * CDIM + tid;
        sm += bf16f(XH[idx]) + bf16f(XL[idx]);
    }
    xm[tid] = sm * (1.f / 128.f);
    __syncthreads();
    if (tid < 128) {
        float a = B1[tid];
        for (int k = 0; k < CDIM; ++k) a = fmaf(xm[k], W1[k * 128 + tid], a);
        a = fmaxf(a, 0.f);
        hred[tid] = a * W2[tid];
    }
    __syncthreads();
    for (int off = 64; off > 0; off >>= 1) {
        if (tid < off) hred[tid] += hred[tid + off];
        __syncthreads();
    }
    if (tid == 0) OUT[b] = hred[0] + B2[0];
}

// ---------------------------------------------------------------------------
extern "C" void kernel_launch(void* const* d_in, const int* in_sizes, int n_in,
                              void* d_out, int out_size, void* d_ws, size_t ws_size,
                              hipStream_t stream) {
    const float* RW  = (const float*)d_in[0];
    const float* POS = (const float*)d_in[1];
    const float* CW1 = (const float*)d_in[2];
    const float* CB1 = (const float*)d_in[3];
    const float* CW2 = (const float*)d_in[4];
    const float* CB2 = (const float*)d_in[5];

    const size_t NTOK = (size_t)NSEQ * SEQN * CDIM;  // 15.7M
    unsigned short* OH = (unsigned short*)d_ws;
    unsigned short* OL = OH + NTOK;
    unsigned short* XH = OL + NTOK;
    unsigned short* XL = XH + NTOK;
    unsigned short* WtHi = XL + NTOK;
    unsigned short* WtLo = WtHi + (size_t)768 * 256;
    unsigned short* W2H = WtLo + (size_t)768 * 256;
    unsigned short* W2L = W2H + (size_t)256 * 256;

    prep_kernel<<<dim3(NSEQ, 4, 8), 256, 0, stream>>>(RW, POS, XH, XL);

    for (int li = 0; li < 2; ++li) {
        const float* qw = (const float*)d_in[6 + 6 * li];
        const float* qb = (const float*)d_in[7 + 6 * li];
        const float* pw = (const float*)d_in[8 + 6 * li];
        const float* pb = (const float*)d_in[9 + 6 * li];
        const float* lg = (const float*)d_in[10 + 6 * li];
        const float* lb = (const float*)d_in[11 + 6 * li];
        wsplit_kernel<<<dim3(8, 24), 256, 0, stream>>>(qw, WtHi, WtLo, 768);
        wsplit_kernel<<<dim3(8, 8), 256, 0, stream>>>(pw, W2H, W2L, 256);
        attn_kernel<<<NSEQ * NH, 256, 0, stream>>>(XH, XL, OH, OL, WtHi, WtLo, qb);
        projln_kernel<<<dim3(NSEQ, 4), 256, 0, stream>>>(OH, OL, XH, XL, W2H, W2L, pb, lg, lb);
    }

    cls_kernel<<<NSEQ, 256, 0, stream>>>(XH, XL, CW1, CB1, CW2, CB2, (float*)d_out);
}